// Round 3
// baseline (3247.184 us; speedup 1.0000x reference)
//
#include <hip/hip_runtime.h>
#include <math.h>
#include <limits.h>

#define H 128
#define V 32000
#define CD 256
#define T_STEPS 21
#define NS 5
#define SOS 1
#define EOS 2
#define B 1024          // unique rows; reference B=5120 is 5 identical copies of each
#define BFULL 5120
#define NCHUNK 250      // V / 128

typedef _Float16 f16;
typedef f16   half8   __attribute__((ext_vector_type(8)));
typedef float floatx4 __attribute__((ext_vector_type(4)));
typedef unsigned short ushort8v __attribute__((ext_vector_type(8)));

__device__ __forceinline__ float bf2f(unsigned short u) {
    return __uint_as_float(((unsigned)u) << 16);
}

// np-faithful f32 sigmoid/tanh: f64 interior, single f32 round per np op.
__device__ __forceinline__ float sig32(float x) {
    float t = (float)exp(-(double)x);
    float r = __fadd_rn(1.0f, t);
    return __fdiv_rn(1.0f, r);
}
__device__ __forceinline__ float tanh32(float x) { return (float)tanh((double)x); }

// ---------------------------------------------------------------- input dtype sniffer
__global__ void k_detect(const unsigned short* __restrict__ e, int* __restrict__ flag) {
    int i = threadIdx.x;
    unsigned short u = e[2 * i];
    int ex = (u >> 7) & 0xFF;
    bool wild = ((u & 0x7FFF) != 0) && (ex < 0x60 || ex > 0x8F);
    unsigned long long m = __ballot(wild);
    if (i == 0) *flag = (m != 0ull) ? 1 : 0;   // 1 = f32 inputs, 0 = bf16
}

// ---------------------------------------------------------------- transcode input -> f32
__global__ void k_transcode(const void* __restrict__ src, float* __restrict__ dst,
                            int n, const int* __restrict__ flag) {
    int i = blockIdx.x * blockDim.x + threadIdx.x;
    if (i >= n) return;
    if (*flag) dst[i] = ((const float*)src)[i];
    else       dst[i] = bf2f(((const unsigned short*)src)[i]);
}

// ---------------------------------------------------------------- W2: coalesced norm + scaled f16 hi/lo split (once per launch)
// Emits wh/wl in FRAGMENT-MAJOR order: f16 index = cb*16384 + kkg*1024 + row_local*8 + j
// (cb = vrow/128, row_local = vrow%128, kkg = k/8) — the exact LDS layout
// k_vscan_mfma consumes, so staging is a linear copy.
__global__ __launch_bounds__(256) void k_wsplit(
    const void* __restrict__ W2_raw, unsigned short* __restrict__ wh,
    unsigned short* __restrict__ wl, float* __restrict__ wn,
    const int* __restrict__ flag) {
    int t = blockIdx.x * 256 + threadIdx.x;       // t in [0, V*H/8)
    const bool isf = (*flag != 0);
    int vrow = t >> 4;                            // vocab row
    int kkg  = t & 15;                            // which 8-wide k group
    float v[8];
    if (isf) {
        float4 f0 = ((const float4*)W2_raw)[2 * t];
        float4 f1 = ((const float4*)W2_raw)[2 * t + 1];
        v[0] = f0.x; v[1] = f0.y; v[2] = f0.z; v[3] = f0.w;
        v[4] = f1.x; v[5] = f1.y; v[6] = f1.z; v[7] = f1.w;
    } else {
        ushort8v u = ((const ushort8v*)W2_raw)[t];
        #pragma unroll
        for (int i = 0; i < 8; ++i) v[i] = bf2f(u[i]);
    }
    float s = 0.f;
    half8 hv, lv;
    #pragma unroll
    for (int i = 0; i < 8; ++i) {
        s += v[i] * v[i];
        float ws = v[i] * 256.0f;
        f16 hh = (f16)ws;
        hv[i] = hh;
        lv[i] = (f16)(ws - (float)hh);
    }
    int cb = vrow >> 7, rloc = vrow & 127;
    long dst = (long)cb * 16384 + kkg * 1024 + rloc * 8;
    *(half8*)((f16*)wh + dst) = hv;
    *(half8*)((f16*)wl + dst) = lv;
    // row norm: 16 consecutive threads share a row
    #pragma unroll
    for (int off = 1; off < 16; off <<= 1) s += __shfl_xor(s, off, 64);
    if (kkg == 0) wn[vrow] = sqrtf(s);
}

// ---------------------------------------------------------------- global max ||w|| (once per launch)
__global__ __launch_bounds__(256) void k_wmax(const float* __restrict__ wn, float* __restrict__ wmax) {
    __shared__ float red[4];
    int tid = threadIdx.x;
    float m = 0.f;
    for (int i = tid; i < V; i += 256) m = fmaxf(m, wn[i]);
    #pragma unroll
    for (int off = 1; off < 64; off <<= 1) m = fmaxf(m, __shfl_xor(m, off, 64));
    if ((tid & 63) == 0) red[tid >> 6] = m;
    __syncthreads();
    if (tid == 0) *wmax = fmaxf(fmaxf(red[0], red[1]), fmaxf(red[2], red[3]));
}

// ---------------------------------------------------------------- init it/unf
__global__ void k_init_state(int* __restrict__ it, int* __restrict__ unf) {
    int i = blockIdx.x * blockDim.x + threadIdx.x;
    if (i < B) { it[i] = SOS; unf[i] = 1; }
}

// ---------------------------------------------------------------- hc = fl32(x @ W_fc.T) + b_fc
__global__ __launch_bounds__(256) void k_init_hc(
    const float* __restrict__ xf, const float* __restrict__ Wfc,
    const float* __restrict__ bfc, float* __restrict__ h, float* __restrict__ c) {
    __shared__ float xl[CD];
    int r = blockIdx.x;
    int j = threadIdx.x;
    xl[j] = xf[(long)r * CD + j];
    __syncthreads();
    const float4* w4 = (const float4*)(Wfc + (long)j * CD);
    double acc = 0.0;
    for (int k4 = 0; k4 < CD / 4; ++k4) {
        float4 w = w4[k4];
        int k = k4 * 4;
        acc += (double)xl[k]     * (double)w.x;
        acc += (double)xl[k + 1] * (double)w.y;
        acc += (double)xl[k + 2] * (double)w.z;
        acc += (double)xl[k + 3] * (double)w.w;
    }
    float hc = __fadd_rn((float)acc, bfc[j]);
    if (j < H) h[(long)r * H + j] = hc;
    else       c[(long)r * H + (j - H)] = hc;
}

// ---------------------------------------------------------------- fused gates + LSTM cell + p-projection
// One block per 8 rows. Phase 1: gates — thread t owns gate columns {t, t+256};
// per output, f64 fma chain over k ascending (identical order to the old
// k_gates, so the rounded f32 gates are bit-identical). Gates live in LDS;
// the 2MB global gates round-trip and one launch per step are eliminated.
// Phases 2+3 are k_cell_proj verbatim (gates read from LDS).
__global__ __launch_bounds__(256) void k_gates_cell(
    const void* __restrict__ embed_raw, float* __restrict__ h, float* __restrict__ c,
    const float* __restrict__ Wih, const float* __restrict__ Whh,
    const float* __restrict__ bih, const float* __restrict__ bhh,
    const int* __restrict__ it,
    const float* __restrict__ W1, const float* __restrict__ b1,
    float* __restrict__ p32, unsigned short* __restrict__ ph,
    unsigned short* __restrict__ pl, const int* __restrict__ flag) {
    __shared__ float As[8][256];    // concat(e_tok, h) per row, 8 KB
    __shared__ float gsh[8][512];   // gates, 16 KB
    __shared__ float hl[8][132];
    const bool isf = (*flag != 0);
    int tid = threadIdx.x;
    int rb = blockIdx.x * 8;

    // ---- stage A rows: thread t loads 8 consecutive elements of row (t>>5)
    {
        int r = tid >> 5, kq = (tid & 31) * 8;
        long row = rb + r;
        int tok = it[row];
        float vals[8];
        if (kq < H) {
            if (isf) {
                const float* e = (const float*)embed_raw + (long)tok * H + kq;
                float4 f0 = *(const float4*)e;
                float4 f1 = *(const float4*)(e + 4);
                vals[0] = f0.x; vals[1] = f0.y; vals[2] = f0.z; vals[3] = f0.w;
                vals[4] = f1.x; vals[5] = f1.y; vals[6] = f1.z; vals[7] = f1.w;
            } else {
                ushort8v u = *(const ushort8v*)((const unsigned short*)embed_raw + (long)tok * H + kq);
                #pragma unroll
                for (int i = 0; i < 8; ++i) vals[i] = bf2f(u[i]);
            }
        } else {
            const float* hp = h + row * H + (kq - H);
            float4 f0 = *(const float4*)hp;
            float4 f1 = *(const float4*)(hp + 4);
            vals[0] = f0.x; vals[1] = f0.y; vals[2] = f0.z; vals[3] = f0.w;
            vals[4] = f1.x; vals[5] = f1.y; vals[6] = f1.z; vals[7] = f1.w;
        }
        #pragma unroll
        for (int i = 0; i < 8; ++i) As[r][kq + i] = vals[i];
    }
    __syncthreads();

    // ---- gates: acc1 = e-part (k<H, Wih), then acc2 = h-part (Whh)
    {
        int c0 = tid, c1 = tid + 256;
        double acc[8][2] = {};
        const float* wi0 = Wih + (long)c0 * H;
        const float* wi1 = Wih + (long)c1 * H;
        for (int k4 = 0; k4 < H / 4; ++k4) {
            float4 w0 = *(const float4*)(wi0 + k4 * 4);
            float4 w1 = *(const float4*)(wi1 + k4 * 4);
            int k = k4 * 4;
            #pragma unroll
            for (int r = 0; r < 8; ++r) {
                float4 a = *(const float4*)(&As[r][k]);   // broadcast read
                double s0 = acc[r][0], s1 = acc[r][1];
                s0 += (double)a.x * (double)w0.x;
                s0 += (double)a.y * (double)w0.y;
                s0 += (double)a.z * (double)w0.z;
                s0 += (double)a.w * (double)w0.w;
                s1 += (double)a.x * (double)w1.x;
                s1 += (double)a.y * (double)w1.y;
                s1 += (double)a.z * (double)w1.z;
                s1 += (double)a.w * (double)w1.w;
                acc[r][0] = s0; acc[r][1] = s1;
            }
        }
        float t1[8][2];
        float bi0 = bih[c0], bi1 = bih[c1];
        #pragma unroll
        for (int r = 0; r < 8; ++r) {
            t1[r][0] = __fadd_rn((float)acc[r][0], bi0);
            t1[r][1] = __fadd_rn((float)acc[r][1], bi1);
            acc[r][0] = 0.0; acc[r][1] = 0.0;
        }
        const float* wh0 = Whh + (long)c0 * H;
        const float* wh1 = Whh + (long)c1 * H;
        for (int k4 = 0; k4 < H / 4; ++k4) {
            float4 w0 = *(const float4*)(wh0 + k4 * 4);
            float4 w1 = *(const float4*)(wh1 + k4 * 4);
            int k = H + k4 * 4;
            #pragma unroll
            for (int r = 0; r < 8; ++r) {
                float4 a = *(const float4*)(&As[r][k]);
                double s0 = acc[r][0], s1 = acc[r][1];
                s0 += (double)a.x * (double)w0.x;
                s0 += (double)a.y * (double)w0.y;
                s0 += (double)a.z * (double)w0.z;
                s0 += (double)a.w * (double)w0.w;
                s1 += (double)a.x * (double)w1.x;
                s1 += (double)a.y * (double)w1.y;
                s1 += (double)a.z * (double)w1.z;
                s1 += (double)a.w * (double)w1.w;
                acc[r][0] = s0; acc[r][1] = s1;
            }
        }
        float bh0 = bhh[c0], bh1 = bhh[c1];
        #pragma unroll
        for (int r = 0; r < 8; ++r) {
            gsh[r][c0] = __fadd_rn(__fadd_rn(t1[r][0], (float)acc[r][0]), bh0);
            gsh[r][c1] = __fadd_rn(__fadd_rn(t1[r][1], (float)acc[r][1]), bh1);
        }
    }
    __syncthreads();

    // ---- cell (k_cell_proj phase 1, gates from LDS)
    #pragma unroll
    for (int i = 0; i < 4; ++i) {
        int lin = tid + i * 256;
        int lr = lin >> 7, j = lin & 127;
        long row = rb + lr;
        float gi = gsh[lr][j], gf = gsh[lr][j + 128], gg = gsh[lr][j + 256], go = gsh[lr][j + 384];
        float cv = c[row * 128 + j];
        float si = sig32(gi);
        float sf = sig32(gf);
        float so = sig32(go);
        float tg = tanh32(gg);
        float cn = __fadd_rn(__fmul_rn(sf, cv), __fmul_rn(si, tg));
        float hn = __fmul_rn(so, tanh32(cn));
        c[row * 128 + j] = cn;
        h[row * 128 + j] = hn;
        hl[lr][j] = hn;
    }
    __syncthreads();

    // ---- proj (k_cell_proj phase 2, verbatim) + p-split
    {
        int j = tid & 127;
        int rbase = (tid >> 7) * 4;
        const float4* w4 = (const float4*)(W1 + (long)j * H);
        double acc[4] = {};
        for (int k4 = 0; k4 < H / 4; ++k4) {
            float4 w = w4[k4];
            int k = k4 * 4;
            #pragma unroll
            for (int rr = 0; rr < 4; ++rr) {
                acc[rr] += (double)hl[rbase + rr][k]     * (double)w.x;
                acc[rr] += (double)hl[rbase + rr][k + 1] * (double)w.y;
                acc[rr] += (double)hl[rbase + rr][k + 2] * (double)w.z;
                acc[rr] += (double)hl[rbase + rr][k + 3] * (double)w.w;
            }
        }
        #pragma unroll
        for (int rr = 0; rr < 4; ++rr) {
            long row = rb + rbase + rr;
            float pv = __fadd_rn((float)acc[rr], b1[j]);
            p32[row * H + j] = pv;
            float ps = pv * 256.0f;
            f16 hh = (f16)ps;
            f16 ll = (f16)(ps - (float)hh);
            ((f16*)ph)[row * H + j] = hh;
            ((f16*)pl)[row * H + j] = ll;
        }
    }
}

// ---------------------------------------------------------------- vocab scan via split-f16 MFMA, LDS-staged B (v3):
// 250 blocks x 512 threads (8 waves): each block owns one vocab chunk cb,
// stages Bh/Bl ONCE (64 KB), then runs TWO row-passes (rows 0-511, 512-1023)
// over the LDS-resident B — 1/4 the staging traffic of v2, single
// scheduling round (250 blocks <= 256 CUs), no tail.
// Per-(row,chunk) epilogue math identical to v2.
__global__ __launch_bounds__(512, 2) void k_vscan_mfma(
    const unsigned short* __restrict__ ph_, const unsigned short* __restrict__ pl_,
    const unsigned short* __restrict__ whf_, const unsigned short* __restrict__ wlf_,
    const float* __restrict__ b2, float* __restrict__ cm, float* __restrict__ cs) {
    __shared__ f16 Bsh[16384];   // 32 KB
    __shared__ f16 Bsl[16384];   // 32 KB
    const f16* ph  = (const f16*)ph_;
    const f16* pl  = (const f16*)pl_;
    int tid  = threadIdx.x;
    int lane = tid & 63, wid = tid >> 6;          // 8 waves
    int tx = lane & 15, kg = lane >> 4;
    int cb = blockIdx.x;
    int vb = cb * 128;

    // stage B tile: linear 64KB copy (global fragment-major == LDS layout)
    {
        const f16* sh = (const f16*)whf_ + (long)cb * 16384;
        const f16* sl = (const f16*)wlf_ + (long)cb * 16384;
        #pragma unroll
        for (int i = 0; i < 4; ++i) {
            int g = tid + 512 * i;               // 16B chunk id, 0..2047
            *(half8*)(Bsh + g * 8) = *(const half8*)(sh + g * 8);
            *(half8*)(Bsl + g * 8) = *(const half8*)(sl + g * 8);
        }
    }
    __syncthreads();

    float bb[8];
    #pragma unroll
    for (int n = 0; n < 8; ++n) bb[n] = b2[vb + n * 16 + tx];
    const float S2 = 1.0f / 65536.0f;

    #pragma unroll 1
    for (int pass = 0; pass < 2; ++pass) {
        int rbw = pass * 512 + wid * 64;

        floatx4 acc[4][8];
        #pragma unroll
        for (int m = 0; m < 4; ++m)
            #pragma unroll
            for (int n = 0; n < 8; ++n)
                acc[m][n] = (floatx4){0.f, 0.f, 0.f, 0.f};

        int aoffs[4];
        #pragma unroll
        for (int m = 0; m < 4; ++m) aoffs[m] = (rbw + m * 16 + tx) * H + kg * 8;

        #pragma unroll
        for (int kk = 0; kk < 4; ++kk) {
            half8 Ah[4], Al[4];
            #pragma unroll
            for (int m = 0; m < 4; ++m) {
                Ah[m] = *(const half8*)(ph + aoffs[m] + kk * 32);
                Al[m] = *(const half8*)(pl + aoffs[m] + kk * 32);
            }
            int bbase = (kk * 4 + kg) * 1024 + tx * 8;
            #pragma unroll
            for (int n = 0; n < 8; ++n) {
                half8 Bh = *(const half8*)(Bsh + bbase + n * 128);
                half8 Bl = *(const half8*)(Bsl + bbase + n * 128);
                #pragma unroll
                for (int m = 0; m < 4; ++m)
                    acc[m][n] = __builtin_amdgcn_mfma_f32_16x16x32_f16(Ah[m], Bh, acc[m][n], 0, 0, 0);
                #pragma unroll
                for (int m = 0; m < 4; ++m)
                    acc[m][n] = __builtin_amdgcn_mfma_f32_16x16x32_f16(Ah[m], Bl, acc[m][n], 0, 0, 0);
                #pragma unroll
                for (int m = 0; m < 4; ++m)
                    acc[m][n] = __builtin_amdgcn_mfma_f32_16x16x32_f16(Al[m], Bh, acc[m][n], 0, 0, 0);
            }
        }

        // epilogue: descale (exact 2^-16), bias, per-(row,chunk) max + expf-sum.
        // C/D layout: col = lane&15 (tx), row = kg*4 + reg.
        #pragma unroll
        for (int m = 0; m < 4; ++m) {
            #pragma unroll
            for (int r = 0; r < 4; ++r) {
                float mxr = -__builtin_inff();
                float sr = 0.f;
                #pragma unroll
                for (int n = 0; n < 8; ++n) {
                    float l = acc[m][n][r] * S2 + bb[n];
                    mxr = fmaxf(mxr, l);
                    sr += __expf(l);
                }
                #pragma unroll
                for (int off = 1; off < 16; off <<= 1) {
                    mxr = fmaxf(mxr, __shfl_xor(mxr, off, 64));
                    sr += __shfl_xor(sr, off, 64);
                }
                if (tx == 0) {
                    long row = rbw + m * 16 + kg * 4 + r;
                    cm[row * NCHUNK + cb] = mxr;
                    cs[row * NCHUNK + cb] = sr;
                }
            }
        }
    }
}

// ---------------------------------------------------------------- finalize: norm-bounded candidate set, exact f64 rescue
// 4 rows per block (one wave each); all reductions are per-wave-64, math
// identical to the single-wave version.
__global__ __launch_bounds__(256) void k_final(
    const float* __restrict__ cm, const float* __restrict__ cs,
    const float* __restrict__ p32, const void* __restrict__ W2_raw,
    const float* __restrict__ b2, const float* __restrict__ wmax,
    int* __restrict__ it, int* __restrict__ unf,
    float* __restrict__ out, int t, const int* __restrict__ flag) {
    const bool isf = (*flag != 0);
    int r = blockIdx.x * 4 + (threadIdx.x >> 6);
    int lane = threadIdx.x & 63;
    const float* cmr = cm + (long)r * NCHUNK;
    const float* csr = cs + (long)r * NCHUNK;
    const float* pr = p32 + (long)r * H;

    // ||p||
    float pa = pr[lane], pb = pr[lane + 64];
    float pn2 = pa * pa + pb * pb;
    #pragma unroll
    for (int off = 1; off < 64; off <<= 1) pn2 += __shfl_xor(pn2, off, 64);
    // rigorous window for the split-f16 MFMA scan:
    // 2*delta <= 2*(~400*2^-24 + 3*2^-22)*||p||*||w|| + flush/round slack
    float eps = 6.0e-5f * sqrtf(pn2) * (*wmax) + 3e-5f;

    float marr[4];
    float AM = -__builtin_inff();
    #pragma unroll
    for (int i = 0; i < 4; ++i) {
        int cc = lane + 64 * i;
        marr[i] = (cc < NCHUNK) ? cmr[cc] : -__builtin_inff();
        AM = fmaxf(AM, marr[i]);
    }
    #pragma unroll
    for (int off = 1; off < 64; off <<= 1) AM = fmaxf(AM, __shfl_xor(AM, off, 64));
    double S = 0.0;
    #pragma unroll
    for (int i = 0; i < 4; ++i) {
        int cc = lane + 64 * i;
        if (cc < NCHUNK) S += (double)csr[cc];
    }
    #pragma unroll
    for (int off = 1; off < 64; off <<= 1) S += __shfl_xor(S, off, 64);

    // pass A: exact f64-recipe max over candidate chunks -> exact global max M
    float M = -__builtin_inff();
    #pragma unroll 1
    for (int i = 0; i < 4; ++i) {
        unsigned long long mask = __ballot(marr[i] >= AM - eps);
        while (mask) {
            int b = __ffsll(mask) - 1;
            mask &= mask - 1;
            int cc = i * 64 + b;
            #pragma unroll
            for (int q = 0; q < 2; ++q) {
                int v = cc * 128 + q * 64 + lane;
                double acc = 0.0;
                if (isf) {
                    const float* wv = (const float*)W2_raw + (long)v * H;
                    for (int k = 0; k < H; ++k) acc += (double)pr[k] * (double)wv[k];
                } else {
                    const unsigned short* wv = (const unsigned short*)W2_raw + (long)v * H;
                    for (int k = 0; k < H; ++k) acc += (double)pr[k] * (double)bf2f(wv[k]);
                }
                float l = __fadd_rn((float)acc, b2[v]);
                M = fmaxf(M, l);
            }
        }
    }
    #pragma unroll
    for (int off = 1; off < 64; off <<= 1) M = fmaxf(M, __shfl_xor(M, off, 64));

    float L = (float)(log(S) - (double)M);
    float negL = __fsub_rn(0.0f, L);

    // pass B: first v (ascending) whose f32 logprob equals the max logprob -L
    int best = INT_MAX;
    #pragma unroll 1
    for (int i = 0; i < 4 && best == INT_MAX; ++i) {
        unsigned long long mask = __ballot(marr[i] >= AM - eps);
        while (mask && best == INT_MAX) {
            int b = __ffsll(mask) - 1;
            mask &= mask - 1;
            int cc = i * 64 + b;
            int hit = INT_MAX;
            #pragma unroll
            for (int q = 0; q < 2; ++q) {
                int v = cc * 128 + q * 64 + lane;
                double acc = 0.0;
                if (isf) {
                    const float* wv = (const float*)W2_raw + (long)v * H;
                    for (int k = 0; k < H; ++k) acc += (double)pr[k] * (double)wv[k];
                } else {
                    const unsigned short* wv = (const unsigned short*)W2_raw + (long)v * H;
                    for (int k = 0; k < H; ++k) acc += (double)pr[k] * (double)bf2f(wv[k]);
                }
                float l  = __fadd_rn((float)acc, b2[v]);
                float lp = __fsub_rn(__fsub_rn(l, M), L);
                if (lp == negL && v < hit) hit = v;
            }
            #pragma unroll
            for (int off = 1; off < 64; off <<= 1) {
                int oh = __shfl_xor(hit, off, 64);
                hit = (oh < hit) ? oh : hit;
            }
            if (hit != INT_MAX) best = hit;
        }
    }
    int bi = (best == INT_MAX) ? 0 : best;

    int unfr = unf[r];
    float lp = negL;
    int itn = unfr ? bi : 0;
    int unfn = (unfr && itn != EOS) ? 1 : 0;
    if (lane == 0) { it[r] = itn; unf[r] = unfn; }
    if (lane < NS) {
        long ro = (long)r * NS + lane;
        out[ro * T_STEPS + t] = (float)itn;
        out[(long)BFULL * T_STEPS + ro * T_STEPS + t] = lp;
        out[2L * BFULL * T_STEPS + ro * T_STEPS + t] = unfr ? 1.0f : 0.0f;
    }
}

// ---------------------------------------------------------------- launch
extern "C" void kernel_launch(void* const* d_in, const int* in_sizes, int n_in,
                              void* d_out, int out_size, void* d_ws, size_t ws_size,
                              hipStream_t stream) {
    float* out = (float*)d_out;

    char* w = (char*)d_ws;
    float* fin[12];
    for (int i = 0; i < 12; ++i) {
        if (i == 1 || i == 10) { fin[i] = nullptr; continue; }   // embed/W2 read raw
        fin[i] = (float*)w;
        size_t bytes = ((size_t)in_sizes[i] * 4 + 15) & ~(size_t)15;
        w += bytes;
    }
    float*  h     = (float*) w; w += (size_t)B * H * 4;
    float*  c     = (float*) w; w += (size_t)B * H * 4;
    float*  p32   = (float*) w; w += (size_t)B * H * 4;
    float*  cm    = (float*) w; w += (size_t)B * NCHUNK * 4;
    float*  cs    = (float*) w; w += (size_t)B * NCHUNK * 4;
    float*  wn    = (float*) w; w += (size_t)V * 4;
    float*  wmax  = (float*) w; w += 16;
    int*    it    = (int*)   w; w += (size_t)B * 4;
    int*    unf   = (int*)   w; w += (size_t)B * 4;
    int*    flag  = (int*)   w; w += 16;
    unsigned short* ph = (unsigned short*)w; w += (size_t)B * H * 2;
    unsigned short* pl = (unsigned short*)w; w += (size_t)B * H * 2;
    unsigned short* wh = (unsigned short*)w; w += (size_t)V * H * 2;
    unsigned short* wl = (unsigned short*)w; w += (size_t)V * H * 2;

    k_detect<<<1, 64, 0, stream>>>((const unsigned short*)d_in[1], flag);
    for (int i = 0; i < 12; ++i) {
        if (i == 1 || i == 10) continue;
        int n = in_sizes[i];
        k_transcode<<<(n + 255) / 256, 256, 0, stream>>>(d_in[i], fin[i], n, flag);
    }
    k_wsplit<<<(V * H / 8 + 255) / 256, 256, 0, stream>>>(d_in[10], wh, wl, wn, flag);
    k_wmax<<<1, 256, 0, stream>>>(wn, wmax);

    const float* xf  = fin[0];
    const float* Wfc = fin[2];
    const float* bfc = fin[3];
    const float* Wih = fin[4];
    const float* bih = fin[5];
    const float* Whh = fin[6];
    const float* bhh = fin[7];
    const float* W1  = fin[8];
    const float* b1  = fin[9];
    const float* b2  = fin[11];

    k_init_state<<<(B + 255) / 256, 256, 0, stream>>>(it, unf);
    k_init_hc<<<B, 256, 0, stream>>>(xf, Wfc, bfc, h, c);
    for (int t = 0; t < T_STEPS; ++t) {
        k_gates_cell<<<B / 8, 256, 0, stream>>>(d_in[1], h, c, Wih, Whh, bih, bhh, it,
                                                W1, b1, p32, ph, pl, flag);
        k_vscan_mfma<<<NCHUNK, 512, 0, stream>>>(ph, pl, wh, wl, b2, cm, cs);
        k_final<<<B / 4, 256, 0, stream>>>(cm, cs, p32, d_in[10], b2, wmax, it, unf, out, t, flag);
    }
}

// Round 4
// 2329.404 us; speedup vs baseline: 1.3940x; 1.3940x over previous
//
#include <hip/hip_runtime.h>
#include <math.h>
#include <limits.h>

#define H 128
#define V 32000
#define CD 256
#define T_STEPS 21
#define NS 5
#define SOS 1
#define EOS 2
#define B 1024          // unique rows; reference B=5120 is 5 identical copies of each
#define BFULL 5120
#define NCHUNK 250      // V / 128

typedef _Float16 f16;
typedef f16   half8   __attribute__((ext_vector_type(8)));
typedef float floatx4 __attribute__((ext_vector_type(4)));
typedef unsigned short ushort8v __attribute__((ext_vector_type(8)));

#define AS1 __attribute__((address_space(1)))
#define AS3 __attribute__((address_space(3)))

__device__ __forceinline__ float bf2f(unsigned short u) {
    return __uint_as_float(((unsigned)u) << 16);
}

// np-faithful f32 sigmoid/tanh: f64 interior, single f32 round per np op.
__device__ __forceinline__ float sig32(float x) {
    float t = (float)exp(-(double)x);
    float r = __fadd_rn(1.0f, t);
    return __fdiv_rn(1.0f, r);
}
__device__ __forceinline__ float tanh32(float x) { return (float)tanh((double)x); }

// ---------------------------------------------------------------- input dtype sniffer
__global__ void k_detect(const unsigned short* __restrict__ e, int* __restrict__ flag) {
    int i = threadIdx.x;
    unsigned short u = e[2 * i];
    int ex = (u >> 7) & 0xFF;
    bool wild = ((u & 0x7FFF) != 0) && (ex < 0x60 || ex > 0x8F);
    unsigned long long m = __ballot(wild);
    if (i == 0) *flag = (m != 0ull) ? 1 : 0;   // 1 = f32 inputs, 0 = bf16
}

// ---------------------------------------------------------------- transcode input -> f32
__global__ void k_transcode(const void* __restrict__ src, float* __restrict__ dst,
                            int n, const int* __restrict__ flag) {
    int i = blockIdx.x * blockDim.x + threadIdx.x;
    if (i >= n) return;
    if (*flag) dst[i] = ((const float*)src)[i];
    else       dst[i] = bf2f(((const unsigned short*)src)[i]);
}

// ---------------------------------------------------------------- W2: coalesced norm + scaled f16 hi/lo split (once per launch)
// Emits wh/wl in FRAGMENT-MAJOR order: f16 index = cb*16384 + kkg*1024 + row_local*8 + j
// (cb = vrow/128, row_local = vrow%128, kkg = k/8) — the exact LDS layout
// k_vscan_mfma consumes, so staging is a linear copy.
__global__ __launch_bounds__(256) void k_wsplit(
    const void* __restrict__ W2_raw, unsigned short* __restrict__ wh,
    unsigned short* __restrict__ wl, float* __restrict__ wn,
    const int* __restrict__ flag) {
    int t = blockIdx.x * 256 + threadIdx.x;       // t in [0, V*H/8)
    const bool isf = (*flag != 0);
    int vrow = t >> 4;                            // vocab row
    int kkg  = t & 15;                            // which 8-wide k group
    float v[8];
    if (isf) {
        float4 f0 = ((const float4*)W2_raw)[2 * t];
        float4 f1 = ((const float4*)W2_raw)[2 * t + 1];
        v[0] = f0.x; v[1] = f0.y; v[2] = f0.z; v[3] = f0.w;
        v[4] = f1.x; v[5] = f1.y; v[6] = f1.z; v[7] = f1.w;
    } else {
        ushort8v u = ((const ushort8v*)W2_raw)[t];
        #pragma unroll
        for (int i = 0; i < 8; ++i) v[i] = bf2f(u[i]);
    }
    float s = 0.f;
    half8 hv, lv;
    #pragma unroll
    for (int i = 0; i < 8; ++i) {
        s += v[i] * v[i];
        float ws = v[i] * 256.0f;
        f16 hh = (f16)ws;
        hv[i] = hh;
        lv[i] = (f16)(ws - (float)hh);
    }
    int cb = vrow >> 7, rloc = vrow & 127;
    long dst = (long)cb * 16384 + kkg * 1024 + rloc * 8;
    *(half8*)((f16*)wh + dst) = hv;
    *(half8*)((f16*)wl + dst) = lv;
    // row norm: 16 consecutive threads share a row
    #pragma unroll
    for (int off = 1; off < 16; off <<= 1) s += __shfl_xor(s, off, 64);
    if (kkg == 0) wn[vrow] = sqrtf(s);
}

// ---------------------------------------------------------------- global max ||w|| (once per launch)
__global__ __launch_bounds__(256) void k_wmax(const float* __restrict__ wn, float* __restrict__ wmax) {
    __shared__ float red[4];
    int tid = threadIdx.x;
    float m = 0.f;
    for (int i = tid; i < V; i += 256) m = fmaxf(m, wn[i]);
    #pragma unroll
    for (int off = 1; off < 64; off <<= 1) m = fmaxf(m, __shfl_xor(m, off, 64));
    if ((tid & 63) == 0) red[tid >> 6] = m;
    __syncthreads();
    if (tid == 0) *wmax = fmaxf(fmaxf(red[0], red[1]), fmaxf(red[2], red[3]));
}

// ---------------------------------------------------------------- init it/unf
__global__ void k_init_state(int* __restrict__ it, int* __restrict__ unf) {
    int i = blockIdx.x * blockDim.x + threadIdx.x;
    if (i < B) { it[i] = SOS; unf[i] = 1; }
}

// ---------------------------------------------------------------- hc = fl32(x @ W_fc.T) + b_fc
__global__ __launch_bounds__(256) void k_init_hc(
    const float* __restrict__ xf, const float* __restrict__ Wfc,
    const float* __restrict__ bfc, float* __restrict__ h, float* __restrict__ c) {
    __shared__ float xl[CD];
    int r = blockIdx.x;
    int j = threadIdx.x;
    xl[j] = xf[(long)r * CD + j];
    __syncthreads();
    const float4* w4 = (const float4*)(Wfc + (long)j * CD);
    double acc = 0.0;
    for (int k4 = 0; k4 < CD / 4; ++k4) {
        float4 w = w4[k4];
        int k = k4 * 4;
        acc += (double)xl[k]     * (double)w.x;
        acc += (double)xl[k + 1] * (double)w.y;
        acc += (double)xl[k + 2] * (double)w.z;
        acc += (double)xl[k + 3] * (double)w.w;
    }
    float hc = __fadd_rn((float)acc, bfc[j]);
    if (j < H) h[(long)r * H + j] = hc;
    else       c[(long)r * H + (j - H)] = hc;
}

// ---------------------------------------------------------------- fused gates + LSTM cell + p-projection (v2: 4 rows/block)
// 256 blocks (1/CU). Per-output f64 fma chains in the identical k-ascending
// order as always -> gates/h/c/p32 bit-identical. Gates live in LDS.
__global__ __launch_bounds__(256) void k_gates_cell(
    const void* __restrict__ embed_raw, float* __restrict__ h, float* __restrict__ c,
    const float* __restrict__ Wih, const float* __restrict__ Whh,
    const float* __restrict__ bih, const float* __restrict__ bhh,
    const int* __restrict__ it,
    const float* __restrict__ W1, const float* __restrict__ b1,
    float* __restrict__ p32, unsigned short* __restrict__ ph,
    unsigned short* __restrict__ pl, const int* __restrict__ flag) {
    __shared__ float As[4][256];    // concat(e_tok, h) per row, 4 KB
    __shared__ float gsh[4][512];   // gates, 8 KB
    __shared__ float hl[4][132];
    const bool isf = (*flag != 0);
    int tid = threadIdx.x;
    int rb = blockIdx.x * 4;

    // ---- stage A rows: thread t loads 4 consecutive elements of row (t>>6)
    {
        int r = tid >> 6, kq = (tid & 63) * 4;
        long row = rb + r;
        int tok = it[row];
        float v0, v1, v2, v3;
        if (kq < H) {
            if (isf) {
                float4 f = *(const float4*)((const float*)embed_raw + (long)tok * H + kq);
                v0 = f.x; v1 = f.y; v2 = f.z; v3 = f.w;
            } else {
                ushort4 u = *(const ushort4*)((const unsigned short*)embed_raw + (long)tok * H + kq);
                v0 = bf2f(u.x); v1 = bf2f(u.y); v2 = bf2f(u.z); v3 = bf2f(u.w);
            }
        } else {
            float4 f = *(const float4*)(h + row * H + (kq - H));
            v0 = f.x; v1 = f.y; v2 = f.z; v3 = f.w;
        }
        As[r][kq] = v0; As[r][kq + 1] = v1; As[r][kq + 2] = v2; As[r][kq + 3] = v3;
    }
    __syncthreads();

    // ---- gates: thread owns gate columns {tid, tid+256}
    {
        int c0 = tid, c1 = tid + 256;
        double acc[4][2] = {};
        const float* wi0 = Wih + (long)c0 * H;
        const float* wi1 = Wih + (long)c1 * H;
        for (int k4 = 0; k4 < H / 4; ++k4) {
            float4 w0 = *(const float4*)(wi0 + k4 * 4);
            float4 w1 = *(const float4*)(wi1 + k4 * 4);
            int k = k4 * 4;
            #pragma unroll
            for (int r = 0; r < 4; ++r) {
                float4 a = *(const float4*)(&As[r][k]);   // broadcast read
                double s0 = acc[r][0], s1 = acc[r][1];
                s0 += (double)a.x * (double)w0.x;
                s0 += (double)a.y * (double)w0.y;
                s0 += (double)a.z * (double)w0.z;
                s0 += (double)a.w * (double)w0.w;
                s1 += (double)a.x * (double)w1.x;
                s1 += (double)a.y * (double)w1.y;
                s1 += (double)a.z * (double)w1.z;
                s1 += (double)a.w * (double)w1.w;
                acc[r][0] = s0; acc[r][1] = s1;
            }
        }
        float t1[4][2];
        float bi0 = bih[c0], bi1 = bih[c1];
        #pragma unroll
        for (int r = 0; r < 4; ++r) {
            t1[r][0] = __fadd_rn((float)acc[r][0], bi0);
            t1[r][1] = __fadd_rn((float)acc[r][1], bi1);
            acc[r][0] = 0.0; acc[r][1] = 0.0;
        }
        const float* wh0 = Whh + (long)c0 * H;
        const float* wh1 = Whh + (long)c1 * H;
        for (int k4 = 0; k4 < H / 4; ++k4) {
            float4 w0 = *(const float4*)(wh0 + k4 * 4);
            float4 w1 = *(const float4*)(wh1 + k4 * 4);
            int k = H + k4 * 4;
            #pragma unroll
            for (int r = 0; r < 4; ++r) {
                float4 a = *(const float4*)(&As[r][k]);
                double s0 = acc[r][0], s1 = acc[r][1];
                s0 += (double)a.x * (double)w0.x;
                s0 += (double)a.y * (double)w0.y;
                s0 += (double)a.z * (double)w0.z;
                s0 += (double)a.w * (double)w0.w;
                s1 += (double)a.x * (double)w1.x;
                s1 += (double)a.y * (double)w1.y;
                s1 += (double)a.z * (double)w1.z;
                s1 += (double)a.w * (double)w1.w;
                acc[r][0] = s0; acc[r][1] = s1;
            }
        }
        float bh0 = bhh[c0], bh1 = bhh[c1];
        #pragma unroll
        for (int r = 0; r < 4; ++r) {
            gsh[r][c0] = __fadd_rn(__fadd_rn(t1[r][0], (float)acc[r][0]), bh0);
            gsh[r][c1] = __fadd_rn(__fadd_rn(t1[r][1], (float)acc[r][1]), bh1);
        }
    }
    __syncthreads();

    // ---- cell (gates from LDS): 512 outputs, 2 per thread
    #pragma unroll
    for (int i = 0; i < 2; ++i) {
        int lin = tid + i * 256;
        int lr = lin >> 7, j = lin & 127;
        long row = rb + lr;
        float gi = gsh[lr][j], gf = gsh[lr][j + 128], gg = gsh[lr][j + 256], go = gsh[lr][j + 384];
        float cv = c[row * 128 + j];
        float si = sig32(gi);
        float sf = sig32(gf);
        float so = sig32(go);
        float tg = tanh32(gg);
        float cn = __fadd_rn(__fmul_rn(sf, cv), __fmul_rn(si, tg));
        float hn = __fmul_rn(so, tanh32(cn));
        c[row * 128 + j] = cn;
        h[row * 128 + j] = hn;
        hl[lr][j] = hn;
    }
    __syncthreads();

    // ---- proj + p-split: thread j owns 2 rows
    {
        int j = tid & 127;
        int rbase = (tid >> 7) * 2;
        const float4* w4 = (const float4*)(W1 + (long)j * H);
        double acc[2] = {};
        for (int k4 = 0; k4 < H / 4; ++k4) {
            float4 w = w4[k4];
            int k = k4 * 4;
            #pragma unroll
            for (int rr = 0; rr < 2; ++rr) {
                acc[rr] += (double)hl[rbase + rr][k]     * (double)w.x;
                acc[rr] += (double)hl[rbase + rr][k + 1] * (double)w.y;
                acc[rr] += (double)hl[rbase + rr][k + 2] * (double)w.z;
                acc[rr] += (double)hl[rbase + rr][k + 3] * (double)w.w;
            }
        }
        #pragma unroll
        for (int rr = 0; rr < 2; ++rr) {
            long row = rb + rbase + rr;
            float pv = __fadd_rn((float)acc[rr], b1[j]);
            p32[row * H + j] = pv;
            float ps = pv * 256.0f;
            f16 hh = (f16)ps;
            f16 ll = (f16)(ps - (float)hh);
            ((f16*)ph)[row * H + j] = hh;
            ((f16*)pl)[row * H + j] = ll;
        }
    }
}

// ---------------------------------------------------------------- vocab scan via split-f16 MFMA (v4):
// round-2 geometry (1024 blocks x 256 thr, 4 waves, 2 blocks/CU, XCD-grouped
// swizzle) + TRANSPOSED cm/cs [cb][row] (coalesced writes — kills the
// write-allocate L2 thrash that round 3 exposed) + global_load_lds staging
// (linear copy, 16B/lane, no VGPR round-trip; m97 pattern).
__global__ __launch_bounds__(256, 2) void k_vscan_mfma(
    const unsigned short* __restrict__ ph_, const unsigned short* __restrict__ pl_,
    const unsigned short* __restrict__ whf_, const unsigned short* __restrict__ wlf_,
    const float* __restrict__ b2, float* __restrict__ cmT, float* __restrict__ csT) {
    __shared__ f16 Bsh[16384];   // 32 KB
    __shared__ f16 Bsl[16384];   // 32 KB
    const f16* ph  = (const f16*)ph_;
    const f16* pl  = (const f16*)pl_;
    int tid  = threadIdx.x;
    int lane = tid & 63, wid = tid >> 6;
    int tx = lane & 15, kg = lane >> 4;

    // bid = hi*32 + rb*8 + xcd  ->  cb = hi*8 + xcd  (same cb -> same bid%8 -> same XCD)
    int bid = blockIdx.x;
    int xcd = bid & 7, rb = (bid >> 3) & 3, hi = bid >> 5;
    int cb = hi * 8 + xcd;
    if (cb >= NCHUNK) return;
    int rbw = rb * 256 + wid * 64;
    int vb  = cb * 128;

    // stage B tile: linear 64KB direct-to-LDS (global fragment-major == LDS layout)
    {
        const f16* sh = (const f16*)whf_ + (long)cb * 16384;
        const f16* sl = (const f16*)wlf_ + (long)cb * 16384;
        #pragma unroll
        for (int i = 0; i < 8; ++i) {
            int g = tid + 256 * i;               // 16B chunk id, 0..2047
            __builtin_amdgcn_global_load_lds(
                (const AS1 void*)(const void*)(sh + (long)g * 8),
                (AS3 void*)(void*)(Bsh + g * 8), 16, 0, 0);
            __builtin_amdgcn_global_load_lds(
                (const AS1 void*)(const void*)(sl + (long)g * 8),
                (AS3 void*)(void*)(Bsl + g * 8), 16, 0, 0);
        }
    }
    __syncthreads();   // drains vmcnt before barrier (compiler-emitted waitcnt)

    floatx4 acc[4][8];
    #pragma unroll
    for (int m = 0; m < 4; ++m)
        #pragma unroll
        for (int n = 0; n < 8; ++n)
            acc[m][n] = (floatx4){0.f, 0.f, 0.f, 0.f};

    int aoffs[4];
    #pragma unroll
    for (int m = 0; m < 4; ++m) aoffs[m] = (rbw + m * 16 + tx) * H + kg * 8;

    #pragma unroll
    for (int kk = 0; kk < 4; ++kk) {
        half8 Ah[4], Al[4];
        #pragma unroll
        for (int m = 0; m < 4; ++m) {
            Ah[m] = *(const half8*)(ph + aoffs[m] + kk * 32);
            Al[m] = *(const half8*)(pl + aoffs[m] + kk * 32);
        }
        int bbase = (kk * 4 + kg) * 1024 + tx * 8;
        #pragma unroll
        for (int n = 0; n < 8; ++n) {
            half8 Bh = *(const half8*)(Bsh + bbase + n * 128);
            half8 Bl = *(const half8*)(Bsl + bbase + n * 128);
            #pragma unroll
            for (int m = 0; m < 4; ++m)
                acc[m][n] = __builtin_amdgcn_mfma_f32_16x16x32_f16(Ah[m], Bh, acc[m][n], 0, 0, 0);
            #pragma unroll
            for (int m = 0; m < 4; ++m)
                acc[m][n] = __builtin_amdgcn_mfma_f32_16x16x32_f16(Ah[m], Bl, acc[m][n], 0, 0, 0);
            #pragma unroll
            for (int m = 0; m < 4; ++m)
                acc[m][n] = __builtin_amdgcn_mfma_f32_16x16x32_f16(Al[m], Bh, acc[m][n], 0, 0, 0);
        }
    }

    // epilogue: descale (exact 2^-16), bias, per-(row,chunk) max + expf-sum.
    // C/D layout: col = lane&15 (tx), row = kg*4 + reg. Transposed (coalesced) writes.
    const float S2 = 1.0f / 65536.0f;
    float bb[8];
    #pragma unroll
    for (int n = 0; n < 8; ++n) bb[n] = b2[vb + n * 16 + tx];
    #pragma unroll
    for (int m = 0; m < 4; ++m) {
        #pragma unroll
        for (int r = 0; r < 4; ++r) {
            float mxr = -__builtin_inff();
            float sr = 0.f;
            #pragma unroll
            for (int n = 0; n < 8; ++n) {
                float l = acc[m][n][r] * S2 + bb[n];
                mxr = fmaxf(mxr, l);
                sr += __expf(l);
            }
            #pragma unroll
            for (int off = 1; off < 16; off <<= 1) {
                mxr = fmaxf(mxr, __shfl_xor(mxr, off, 64));
                sr += __shfl_xor(sr, off, 64);
            }
            if (tx == 0) {
                int row = rbw + m * 16 + kg * 4 + r;
                cmT[(long)cb * B + row] = mxr;
                csT[(long)cb * B + row] = sr;
            }
        }
    }
}

// ---------------------------------------------------------------- finalize: norm-bounded candidate set, exact f64 rescue
// 4 rows per block (one wave each); cm/cs now transposed [cb][row].
__global__ __launch_bounds__(256) void k_final(
    const float* __restrict__ cmT, const float* __restrict__ csT,
    const float* __restrict__ p32, const void* __restrict__ W2_raw,
    const float* __restrict__ b2, const float* __restrict__ wmax,
    int* __restrict__ it, int* __restrict__ unf,
    float* __restrict__ out, int t, const int* __restrict__ flag) {
    const bool isf = (*flag != 0);
    int r = blockIdx.x * 4 + (threadIdx.x >> 6);
    int lane = threadIdx.x & 63;
    const float* pr = p32 + (long)r * H;

    // ||p||
    float pa = pr[lane], pb = pr[lane + 64];
    float pn2 = pa * pa + pb * pb;
    #pragma unroll
    for (int off = 1; off < 64; off <<= 1) pn2 += __shfl_xor(pn2, off, 64);
    // rigorous window for the split-f16 MFMA scan:
    // 2*delta <= 2*(~400*2^-24 + 3*2^-22)*||p||*||w|| + flush/round slack
    float eps = 6.0e-5f * sqrtf(pn2) * (*wmax) + 3e-5f;

    float marr[4];
    float AM = -__builtin_inff();
    #pragma unroll
    for (int i = 0; i < 4; ++i) {
        int cc = lane + 64 * i;
        marr[i] = (cc < NCHUNK) ? cmT[(long)cc * B + r] : -__builtin_inff();
        AM = fmaxf(AM, marr[i]);
    }
    #pragma unroll
    for (int off = 1; off < 64; off <<= 1) AM = fmaxf(AM, __shfl_xor(AM, off, 64));
    double S = 0.0;
    #pragma unroll
    for (int i = 0; i < 4; ++i) {
        int cc = lane + 64 * i;
        if (cc < NCHUNK) S += (double)csT[(long)cc * B + r];
    }
    #pragma unroll
    for (int off = 1; off < 64; off <<= 1) S += __shfl_xor(S, off, 64);

    // pass A: exact f64-recipe max over candidate chunks -> exact global max M
    float M = -__builtin_inff();
    #pragma unroll 1
    for (int i = 0; i < 4; ++i) {
        unsigned long long mask = __ballot(marr[i] >= AM - eps);
        while (mask) {
            int b = __ffsll(mask) - 1;
            mask &= mask - 1;
            int cc = i * 64 + b;
            #pragma unroll
            for (int q = 0; q < 2; ++q) {
                int v = cc * 128 + q * 64 + lane;
                double acc = 0.0;
                if (isf) {
                    const float* wv = (const float*)W2_raw + (long)v * H;
                    for (int k = 0; k < H; ++k) acc += (double)pr[k] * (double)wv[k];
                } else {
                    const unsigned short* wv = (const unsigned short*)W2_raw + (long)v * H;
                    for (int k = 0; k < H; ++k) acc += (double)pr[k] * (double)bf2f(wv[k]);
                }
                float l = __fadd_rn((float)acc, b2[v]);
                M = fmaxf(M, l);
            }
        }
    }
    #pragma unroll
    for (int off = 1; off < 64; off <<= 1) M = fmaxf(M, __shfl_xor(M, off, 64));

    float L = (float)(log(S) - (double)M);
    float negL = __fsub_rn(0.0f, L);

    // pass B: first v (ascending) whose f32 logprob equals the max logprob -L
    int best = INT_MAX;
    #pragma unroll 1
    for (int i = 0; i < 4 && best == INT_MAX; ++i) {
        unsigned long long mask = __ballot(marr[i] >= AM - eps);
        while (mask && best == INT_MAX) {
            int b = __ffsll(mask) - 1;
            mask &= mask - 1;
            int cc = i * 64 + b;
            int hit = INT_MAX;
            #pragma unroll
            for (int q = 0; q < 2; ++q) {
                int v = cc * 128 + q * 64 + lane;
                double acc = 0.0;
                if (isf) {
                    const float* wv = (const float*)W2_raw + (long)v * H;
                    for (int k = 0; k < H; ++k) acc += (double)pr[k] * (double)wv[k];
                } else {
                    const unsigned short* wv = (const unsigned short*)W2_raw + (long)v * H;
                    for (int k = 0; k < H; ++k) acc += (double)pr[k] * (double)bf2f(wv[k]);
                }
                float l  = __fadd_rn((float)acc, b2[v]);
                float lp = __fsub_rn(__fsub_rn(l, M), L);
                if (lp == negL && v < hit) hit = v;
            }
            #pragma unroll
            for (int off = 1; off < 64; off <<= 1) {
                int oh = __shfl_xor(hit, off, 64);
                hit = (oh < hit) ? oh : hit;
            }
            if (hit != INT_MAX) best = hit;
        }
    }
    int bi = (best == INT_MAX) ? 0 : best;

    int unfr = unf[r];
    float lp = negL;
    int itn = unfr ? bi : 0;
    int unfn = (unfr && itn != EOS) ? 1 : 0;
    if (lane == 0) { it[r] = itn; unf[r] = unfn; }
    if (lane < NS) {
        long ro = (long)r * NS + lane;
        out[ro * T_STEPS + t] = (float)itn;
        out[(long)BFULL * T_STEPS + ro * T_STEPS + t] = lp;
        out[2L * BFULL * T_STEPS + ro * T_STEPS + t] = unfr ? 1.0f : 0.0f;
    }
}

// ---------------------------------------------------------------- launch
extern "C" void kernel_launch(void* const* d_in, const int* in_sizes, int n_in,
                              void* d_out, int out_size, void* d_ws, size_t ws_size,
                              hipStream_t stream) {
    float* out = (float*)d_out;

    char* w = (char*)d_ws;
    float* fin[12];
    for (int i = 0; i < 12; ++i) {
        if (i == 1 || i == 10) { fin[i] = nullptr; continue; }   // embed/W2 read raw
        fin[i] = (float*)w;
        size_t bytes = ((size_t)in_sizes[i] * 4 + 15) & ~(size_t)15;
        w += bytes;
    }
    float*  h     = (float*) w; w += (size_t)B * H * 4;
    float*  c     = (float*) w; w += (size_t)B * H * 4;
    float*  p32   = (float*) w; w += (size_t)B * H * 4;
    float*  cm    = (float*) w; w += (size_t)B * NCHUNK * 4;
    float*  cs    = (float*) w; w += (size_t)B * NCHUNK * 4;
    float*  wn    = (float*) w; w += (size_t)V * 4;
    float*  wmax  = (float*) w; w += 16;
    int*    it    = (int*)   w; w += (size_t)B * 4;
    int*    unf   = (int*)   w; w += (size_t)B * 4;
    int*    flag  = (int*)   w; w += 16;
    unsigned short* ph = (unsigned short*)w; w += (size_t)B * H * 2;
    unsigned short* pl = (unsigned short*)w; w += (size_t)B * H * 2;
    unsigned short* wh = (unsigned short*)w; w += (size_t)V * H * 2;
    unsigned short* wl = (unsigned short*)w; w += (size_t)V * H * 2;

    k_detect<<<1, 64, 0, stream>>>((const unsigned short*)d_in[1], flag);
    for (int i = 0; i < 12; ++i) {
        if (i == 1 || i == 10) continue;
        int n = in_sizes[i];
        k_transcode<<<(n + 255) / 256, 256, 0, stream>>>(d_in[i], fin[i], n, flag);
    }
    k_wsplit<<<(V * H / 8 + 255) / 256, 256, 0, stream>>>(d_in[10], wh, wl, wn, flag);
    k_wmax<<<1, 256, 0, stream>>>(wn, wmax);

    const float* xf  = fin[0];
    const float* Wfc = fin[2];
    const float* bfc = fin[3];
    const float* Wih = fin[4];
    const float* bih = fin[5];
    const float* Whh = fin[6];
    const float* bhh = fin[7];
    const float* W1  = fin[8];
    const float* b1  = fin[9];
    const float* b2  = fin[11];

    k_init_state<<<(B + 255) / 256, 256, 0, stream>>>(it, unf);
    k_init_hc<<<B, 256, 0, stream>>>(xf, Wfc, bfc, h, c);
    for (int t = 0; t < T_STEPS; ++t) {
        k_gates_cell<<<B / 4, 256, 0, stream>>>(d_in[1], h, c, Wih, Whh, bih, bhh, it,
                                                W1, b1, p32, ph, pl, flag);
        k_vscan_mfma<<<1024, 256, 0, stream>>>(ph, pl, wh, wl, b2, cm, cs);
        k_final<<<B / 4, 256, 0, stream>>>(cm, cs, p32, d_in[10], b2, wmax, it, unf, out, t, flag);
    }
}

// Round 6
// 2191.963 us; speedup vs baseline: 1.4814x; 1.0627x over previous
//
#include <hip/hip_runtime.h>
#include <math.h>
#include <limits.h>

#define H 128
#define V 32000
#define CD 256
#define T_STEPS 21
#define NS 5
#define SOS 1
#define EOS 2
#define B 1024          // unique rows; reference B=5120 is 5 identical copies of each
#define BFULL 5120
#define NCHUNK 250      // V / 128

typedef _Float16 f16;
typedef f16   half8   __attribute__((ext_vector_type(8)));
typedef float floatx4 __attribute__((ext_vector_type(4)));
typedef unsigned short ushort8v __attribute__((ext_vector_type(8)));

#define AS1 __attribute__((address_space(1)))
#define AS3 __attribute__((address_space(3)))

__device__ __forceinline__ float bf2f(unsigned short u) {
    return __uint_as_float(((unsigned)u) << 16);
}

// np-faithful f32 sigmoid/tanh: f64 interior, single f32 round per np op.
__device__ __forceinline__ float sig32(float x) {
    float t = (float)exp(-(double)x);
    float r = __fadd_rn(1.0f, t);
    return __fdiv_rn(1.0f, r);
}
__device__ __forceinline__ float tanh32(float x) { return (float)tanh((double)x); }

// ---------------------------------------------------------------- input dtype sniffer
__global__ void k_detect(const unsigned short* __restrict__ e, int* __restrict__ flag) {
    int i = threadIdx.x;
    unsigned short u = e[2 * i];
    int ex = (u >> 7) & 0xFF;
    bool wild = ((u & 0x7FFF) != 0) && (ex < 0x60 || ex > 0x8F);
    unsigned long long m = __ballot(wild);
    if (i == 0) *flag = (m != 0ull) ? 1 : 0;   // 1 = f32 inputs, 0 = bf16
}

// ---------------------------------------------------------------- transcode ALL f32-bound inputs in one dispatch
struct TCArgs {
    const void* src[12];
    float*      dst[12];
    int         n[12];
};
__global__ __launch_bounds__(256) void k_transcode_all(TCArgs tc, const int* __restrict__ flag) {
    int which = blockIdx.y;
    float* d = tc.dst[which];
    if (d == nullptr) return;
    int i = blockIdx.x * 256 + threadIdx.x;
    if (i >= tc.n[which]) return;
    if (*flag) d[i] = ((const float*)tc.src[which])[i];
    else       d[i] = bf2f(((const unsigned short*)tc.src[which])[i]);
}

// ---------------------------------------------------------------- W2: coalesced norm + scaled f16 hi/lo split (once per launch)
// Emits wh/wl in FRAGMENT-MAJOR order: f16 index = cb*16384 + kkg*1024 + row_local*8 + j
// (cb = vrow/128, row_local = vrow%128, kkg = k/8) — the exact LDS layout
// k_vscan_mfma consumes, so staging is a linear copy.
__global__ __launch_bounds__(256) void k_wsplit(
    const void* __restrict__ W2_raw, unsigned short* __restrict__ wh,
    unsigned short* __restrict__ wl, float* __restrict__ wn,
    const int* __restrict__ flag) {
    int t = blockIdx.x * 256 + threadIdx.x;       // t in [0, V*H/8)
    const bool isf = (*flag != 0);
    int vrow = t >> 4;                            // vocab row
    int kkg  = t & 15;                            // which 8-wide k group
    float v[8];
    if (isf) {
        float4 f0 = ((const float4*)W2_raw)[2 * t];
        float4 f1 = ((const float4*)W2_raw)[2 * t + 1];
        v[0] = f0.x; v[1] = f0.y; v[2] = f0.z; v[3] = f0.w;
        v[4] = f1.x; v[5] = f1.y; v[6] = f1.z; v[7] = f1.w;
    } else {
        ushort8v u = ((const ushort8v*)W2_raw)[t];
        #pragma unroll
        for (int i = 0; i < 8; ++i) v[i] = bf2f(u[i]);
    }
    float s = 0.f;
    half8 hv, lv;
    #pragma unroll
    for (int i = 0; i < 8; ++i) {
        s += v[i] * v[i];
        float ws = v[i] * 256.0f;
        f16 hh = (f16)ws;
        hv[i] = hh;
        lv[i] = (f16)(ws - (float)hh);
    }
    int cb = vrow >> 7, rloc = vrow & 127;
    long dst = (long)cb * 16384 + kkg * 1024 + rloc * 8;
    *(half8*)((f16*)wh + dst) = hv;
    *(half8*)((f16*)wl + dst) = lv;
    // row norm: 16 consecutive threads share a row
    #pragma unroll
    for (int off = 1; off < 16; off <<= 1) s += __shfl_xor(s, off, 64);
    if (kkg == 0) wn[vrow] = sqrtf(s);
}

// ---------------------------------------------------------------- prep: wmax (block 4) + it/unf init (blocks 0-3)
__global__ __launch_bounds__(256) void k_prep(
    const float* __restrict__ wn, float* __restrict__ wmax,
    int* __restrict__ it, int* __restrict__ unf) {
    int tid = threadIdx.x;
    if (blockIdx.x < 4) {
        int i = blockIdx.x * 256 + tid;
        it[i] = SOS; unf[i] = 1;
        return;
    }
    __shared__ float red[4];
    float m = 0.f;
    for (int i = tid; i < V; i += 256) m = fmaxf(m, wn[i]);
    #pragma unroll
    for (int off = 1; off < 64; off <<= 1) m = fmaxf(m, __shfl_xor(m, off, 64));
    if ((tid & 63) == 0) red[tid >> 6] = m;
    __syncthreads();
    if (tid == 0) *wmax = fmaxf(fmaxf(red[0], red[1]), fmaxf(red[2], red[3]));
}

// ---------------------------------------------------------------- hc = fl32(x @ W_fc.T) + b_fc
__global__ __launch_bounds__(256) void k_init_hc(
    const float* __restrict__ xf, const float* __restrict__ Wfc,
    const float* __restrict__ bfc, float* __restrict__ h, float* __restrict__ c) {
    __shared__ float xl[CD];
    int r = blockIdx.x;
    int j = threadIdx.x;
    xl[j] = xf[(long)r * CD + j];
    __syncthreads();
    const float4* w4 = (const float4*)(Wfc + (long)j * CD);
    double acc = 0.0;
    for (int k4 = 0; k4 < CD / 4; ++k4) {
        float4 w = w4[k4];
        int k = k4 * 4;
        acc += (double)xl[k]     * (double)w.x;
        acc += (double)xl[k + 1] * (double)w.y;
        acc += (double)xl[k + 2] * (double)w.z;
        acc += (double)xl[k + 3] * (double)w.w;
    }
    float hc = __fadd_rn((float)acc, bfc[j]);
    if (j < H) h[(long)r * H + j] = hc;
    else       c[(long)r * H + (j - H)] = hc;
}

// ---------------------------------------------------------------- fused F(t-1) + G(t):
// 256 blocks x 256 threads, 4 rows each (rows rb..rb+3 owned end-to-end).
// Phase F (t>0): norm-bounded candidate rescue for step t-1 using cm/cs
//   produced by the previous V dispatch (launch boundary = global sync).
//   Writes out[] for t-1 and updates it/unf — same rows this block's G uses,
//   so the handoff is block-local (__syncthreads).
// Phase G: gates+cell+proj, f64 chains in identical k-ascending order
//   (bit-identical to rounds 2-4).
__global__ __launch_bounds__(256) void k_gf(
    const float* __restrict__ cmT, const float* __restrict__ csT,
    const void* __restrict__ W2_raw, const float* __restrict__ b2,
    const float* __restrict__ wmax,
    const void* __restrict__ embed_raw, float* __restrict__ h, float* __restrict__ c,
    const float* __restrict__ Wih, const float* __restrict__ Whh,
    const float* __restrict__ bih, const float* __restrict__ bhh,
    const float* __restrict__ W1, const float* __restrict__ b1,
    float* __restrict__ p32, unsigned short* __restrict__ ph,
    unsigned short* __restrict__ pl,
    int* __restrict__ it, int* __restrict__ unf, float* __restrict__ out,
    int t, const int* __restrict__ flag) {
    __shared__ float As[4][256];    // concat(e_tok, h) per row
    __shared__ float gsh[4][512];   // gates
    __shared__ float hl[4][132];
    const bool isf = (*flag != 0);
    int tid = threadIdx.x;
    int rb = blockIdx.x * 4;
    int lane = tid & 63, wid = tid >> 6;

    // ================= F: finalize step t-1 for row rb+wid =================
    if (t > 0) {
        int r = rb + wid;
        const float* pr = p32 + (long)r * H;

        float pa = pr[lane], pb = pr[lane + 64];
        float pn2 = pa * pa + pb * pb;
        #pragma unroll
        for (int off = 1; off < 64; off <<= 1) pn2 += __shfl_xor(pn2, off, 64);
        // rigorous window for the split-f16 MFMA scan
        float eps = 6.0e-5f * sqrtf(pn2) * (*wmax) + 3e-5f;

        float marr[4];
        float AM = -__builtin_inff();
        #pragma unroll
        for (int i = 0; i < 4; ++i) {
            int cc = lane + 64 * i;
            marr[i] = (cc < NCHUNK) ? cmT[(long)cc * B + r] : -__builtin_inff();
            AM = fmaxf(AM, marr[i]);
        }
        #pragma unroll
        for (int off = 1; off < 64; off <<= 1) AM = fmaxf(AM, __shfl_xor(AM, off, 64));
        double S = 0.0;
        #pragma unroll
        for (int i = 0; i < 4; ++i) {
            int cc = lane + 64 * i;
            if (cc < NCHUNK) S += (double)csT[(long)cc * B + r];
        }
        #pragma unroll
        for (int off = 1; off < 64; off <<= 1) S += __shfl_xor(S, off, 64);

        // pass A: exact f64-recipe max over candidate chunks
        float M = -__builtin_inff();
        #pragma unroll 1
        for (int i = 0; i < 4; ++i) {
            unsigned long long mask = __ballot(marr[i] >= AM - eps);
            while (mask) {
                int bsl = __ffsll(mask) - 1;
                mask &= mask - 1;
                int cc = i * 64 + bsl;
                #pragma unroll
                for (int q = 0; q < 2; ++q) {
                    int v = cc * 128 + q * 64 + lane;
                    double acc = 0.0;
                    if (isf) {
                        const float* wv = (const float*)W2_raw + (long)v * H;
                        for (int k = 0; k < H; ++k) acc += (double)pr[k] * (double)wv[k];
                    } else {
                        const unsigned short* wv = (const unsigned short*)W2_raw + (long)v * H;
                        for (int k = 0; k < H; ++k) acc += (double)pr[k] * (double)bf2f(wv[k]);
                    }
                    float l = __fadd_rn((float)acc, b2[v]);
                    M = fmaxf(M, l);
                }
            }
        }
        #pragma unroll
        for (int off = 1; off < 64; off <<= 1) M = fmaxf(M, __shfl_xor(M, off, 64));

        float L = (float)(log(S) - (double)M);
        float negL = __fsub_rn(0.0f, L);

        // pass B: first v whose f32 logprob equals -L
        int best = INT_MAX;
        #pragma unroll 1
        for (int i = 0; i < 4 && best == INT_MAX; ++i) {
            unsigned long long mask = __ballot(marr[i] >= AM - eps);
            while (mask && best == INT_MAX) {
                int bsl = __ffsll(mask) - 1;
                mask &= mask - 1;
                int cc = i * 64 + bsl;
                int hit = INT_MAX;
                #pragma unroll
                for (int q = 0; q < 2; ++q) {
                    int v = cc * 128 + q * 64 + lane;
                    double acc = 0.0;
                    if (isf) {
                        const float* wv = (const float*)W2_raw + (long)v * H;
                        for (int k = 0; k < H; ++k) acc += (double)pr[k] * (double)wv[k];
                    } else {
                        const unsigned short* wv = (const unsigned short*)W2_raw + (long)v * H;
                        for (int k = 0; k < H; ++k) acc += (double)pr[k] * (double)bf2f(wv[k]);
                    }
                    float l  = __fadd_rn((float)acc, b2[v]);
                    float lp = __fsub_rn(__fsub_rn(l, M), L);
                    if (lp == negL && v < hit) hit = v;
                }
                #pragma unroll
                for (int off = 1; off < 64; off <<= 1) {
                    int oh = __shfl_xor(hit, off, 64);
                    hit = (oh < hit) ? oh : hit;
                }
                if (hit != INT_MAX) best = hit;
            }
        }
        int bi = (best == INT_MAX) ? 0 : best;

        int unfr = unf[r];
        float lp = negL;
        int itn = unfr ? bi : 0;
        int unfn = (unfr && itn != EOS) ? 1 : 0;
        if (lane == 0) { it[r] = itn; unf[r] = unfn; }
        if (lane < NS) {
            long ro = (long)r * NS + lane;
            int tm1 = t - 1;
            out[ro * T_STEPS + tm1] = (float)itn;
            out[(long)BFULL * T_STEPS + ro * T_STEPS + tm1] = lp;
            out[2L * BFULL * T_STEPS + ro * T_STEPS + tm1] = unfr ? 1.0f : 0.0f;
        }
    }
    __syncthreads();

    // ================= G: gates + cell + proj (rows rb..rb+3) =================
    {   // stage As: thread t -> row (tid>>6), 4 consecutive elems
        int r = tid >> 6, kq = (tid & 63) * 4;
        long row = rb + r;
        int tok = it[row];
        float v0, v1, v2, v3;
        if (kq < H) {
            if (isf) {
                float4 f = *(const float4*)((const float*)embed_raw + (long)tok * H + kq);
                v0 = f.x; v1 = f.y; v2 = f.z; v3 = f.w;
            } else {
                ushort4 u = *(const ushort4*)((const unsigned short*)embed_raw + (long)tok * H + kq);
                v0 = bf2f(u.x); v1 = bf2f(u.y); v2 = bf2f(u.z); v3 = bf2f(u.w);
            }
        } else {
            float4 f = *(const float4*)(h + row * H + (kq - H));
            v0 = f.x; v1 = f.y; v2 = f.z; v3 = f.w;
        }
        As[r][kq] = v0; As[r][kq + 1] = v1; As[r][kq + 2] = v2; As[r][kq + 3] = v3;
    }
    __syncthreads();

    {   // gates: thread owns gate columns {tid, tid+256}
        int c0 = tid, c1 = tid + 256;
        double acc[4][2] = {};
        const float* wi0 = Wih + (long)c0 * H;
        const float* wi1 = Wih + (long)c1 * H;
        for (int k4 = 0; k4 < H / 4; ++k4) {
            float4 w0 = *(const float4*)(wi0 + k4 * 4);
            float4 w1 = *(const float4*)(wi1 + k4 * 4);
            int k = k4 * 4;
            #pragma unroll
            for (int r = 0; r < 4; ++r) {
                float4 a = *(const float4*)(&As[r][k]);   // broadcast read
                double s0 = acc[r][0], s1 = acc[r][1];
                s0 += (double)a.x * (double)w0.x;
                s0 += (double)a.y * (double)w0.y;
                s0 += (double)a.z * (double)w0.z;
                s0 += (double)a.w * (double)w0.w;
                s1 += (double)a.x * (double)w1.x;
                s1 += (double)a.y * (double)w1.y;
                s1 += (double)a.z * (double)w1.z;
                s1 += (double)a.w * (double)w1.w;
                acc[r][0] = s0; acc[r][1] = s1;
            }
        }
        float t1[4][2];
        float bi0 = bih[c0], bi1 = bih[c1];
        #pragma unroll
        for (int r = 0; r < 4; ++r) {
            t1[r][0] = __fadd_rn((float)acc[r][0], bi0);
            t1[r][1] = __fadd_rn((float)acc[r][1], bi1);
            acc[r][0] = 0.0; acc[r][1] = 0.0;
        }
        const float* wh0 = Whh + (long)c0 * H;
        const float* wh1 = Whh + (long)c1 * H;
        for (int k4 = 0; k4 < H / 4; ++k4) {
            float4 w0 = *(const float4*)(wh0 + k4 * 4);
            float4 w1 = *(const float4*)(wh1 + k4 * 4);
            int k = H + k4 * 4;
            #pragma unroll
            for (int r = 0; r < 4; ++r) {
                float4 a = *(const float4*)(&As[r][k]);
                double s0 = acc[r][0], s1 = acc[r][1];
                s0 += (double)a.x * (double)w0.x;
                s0 += (double)a.y * (double)w0.y;
                s0 += (double)a.z * (double)w0.z;
                s0 += (double)a.w * (double)w0.w;
                s1 += (double)a.x * (double)w1.x;
                s1 += (double)a.y * (double)w1.y;
                s1 += (double)a.z * (double)w1.z;
                s1 += (double)a.w * (double)w1.w;
                acc[r][0] = s0; acc[r][1] = s1;
            }
        }
        float bh0 = bhh[c0], bh1 = bhh[c1];
        #pragma unroll
        for (int r = 0; r < 4; ++r) {
            gsh[r][c0] = __fadd_rn(__fadd_rn(t1[r][0], (float)acc[r][0]), bh0);
            gsh[r][c1] = __fadd_rn(__fadd_rn(t1[r][1], (float)acc[r][1]), bh1);
        }
    }
    __syncthreads();

    // ---- cell (gates from LDS): 512 outputs, 2 per thread
    #pragma unroll
    for (int i = 0; i < 2; ++i) {
        int lin = tid + i * 256;
        int lr = lin >> 7, j = lin & 127;
        long row = rb + lr;
        float gi = gsh[lr][j], gf = gsh[lr][j + 128], gg = gsh[lr][j + 256], go = gsh[lr][j + 384];
        float cv = c[row * 128 + j];
        float si = sig32(gi);
        float sf = sig32(gf);
        float so = sig32(go);
        float tg = tanh32(gg);
        float cn = __fadd_rn(__fmul_rn(sf, cv), __fmul_rn(si, tg));
        float hn = __fmul_rn(so, tanh32(cn));
        c[row * 128 + j] = cn;
        h[row * 128 + j] = hn;
        hl[lr][j] = hn;
    }
    __syncthreads();

    // ---- proj + p-split: thread j owns 2 rows
    {
        int j = tid & 127;
        int rbase = (tid >> 7) * 2;
        const float4* w4 = (const float4*)(W1 + (long)j * H);
        double acc[2] = {};
        for (int k4 = 0; k4 < H / 4; ++k4) {
            float4 w = w4[k4];
            int k = k4 * 4;
            #pragma unroll
            for (int rr = 0; rr < 2; ++rr) {
                acc[rr] += (double)hl[rbase + rr][k]     * (double)w.x;
                acc[rr] += (double)hl[rbase + rr][k + 1] * (double)w.y;
                acc[rr] += (double)hl[rbase + rr][k + 2] * (double)w.z;
                acc[rr] += (double)hl[rbase + rr][k + 3] * (double)w.w;
            }
        }
        #pragma unroll
        for (int rr = 0; rr < 2; ++rr) {
            long row = rb + rbase + rr;
            float pv = __fadd_rn((float)acc[rr], b1[j]);
            p32[row * H + j] = pv;
            float ps = pv * 256.0f;
            f16 hh = (f16)ps;
            f16 ll = (f16)(ps - (float)hh);
            ((f16*)ph)[row * H + j] = hh;
            ((f16*)pl)[row * H + j] = ll;
        }
    }
}

// ---------------------------------------------------------------- vocab scan via split-f16 MFMA (round-4 version, unchanged):
// 1024 blocks x 256 thr, 4 waves, 2 blocks/CU, XCD-grouped swizzle,
// transposed cm/cs [cb][row] (coalesced writes), global_load_lds staging.
__global__ __launch_bounds__(256, 2) void k_vscan_mfma(
    const unsigned short* __restrict__ ph_, const unsigned short* __restrict__ pl_,
    const unsigned short* __restrict__ whf_, const unsigned short* __restrict__ wlf_,
    const float* __restrict__ b2, float* __restrict__ cmT, float* __restrict__ csT) {
    __shared__ f16 Bsh[16384];   // 32 KB
    __shared__ f16 Bsl[16384];   // 32 KB
    const f16* ph  = (const f16*)ph_;
    const f16* pl  = (const f16*)pl_;
    int tid  = threadIdx.x;
    int lane = tid & 63, wid = tid >> 6;
    int tx = lane & 15, kg = lane >> 4;

    // bid = hi*32 + rb*8 + xcd  ->  cb = hi*8 + xcd  (same cb -> same bid%8 -> same XCD)
    int bid = blockIdx.x;
    int xcd = bid & 7, rb = (bid >> 3) & 3, hi = bid >> 5;
    int cb = hi * 8 + xcd;
    if (cb >= NCHUNK) return;
    int rbw = rb * 256 + wid * 64;
    int vb  = cb * 128;

    // stage B tile: linear 64KB direct-to-LDS (global fragment-major == LDS layout)
    {
        const f16* sh = (const f16*)whf_ + (long)cb * 16384;
        const f16* sl = (const f16*)wlf_ + (long)cb * 16384;
        #pragma unroll
        for (int i = 0; i < 8; ++i) {
            int g = tid + 256 * i;               // 16B chunk id, 0..2047
            __builtin_amdgcn_global_load_lds(
                (const AS1 void*)(const void*)(sh + (long)g * 8),
                (AS3 void*)(void*)(Bsh + g * 8), 16, 0, 0);
            __builtin_amdgcn_global_load_lds(
                (const AS1 void*)(const void*)(sl + (long)g * 8),
                (AS3 void*)(void*)(Bsl + g * 8), 16, 0, 0);
        }
    }
    __syncthreads();

    floatx4 acc[4][8];
    #pragma unroll
    for (int m = 0; m < 4; ++m)
        #pragma unroll
        for (int n = 0; n < 8; ++n)
            acc[m][n] = (floatx4){0.f, 0.f, 0.f, 0.f};

    int aoffs[4];
    #pragma unroll
    for (int m = 0; m < 4; ++m) aoffs[m] = (rbw + m * 16 + tx) * H + kg * 8;

    #pragma unroll
    for (int kk = 0; kk < 4; ++kk) {
        half8 Ah[4], Al[4];
        #pragma unroll
        for (int m = 0; m < 4; ++m) {
            Ah[m] = *(const half8*)(ph + aoffs[m] + kk * 32);
            Al[m] = *(const half8*)(pl + aoffs[m] + kk * 32);
        }
        int bbase = (kk * 4 + kg) * 1024 + tx * 8;
        #pragma unroll
        for (int n = 0; n < 8; ++n) {
            half8 Bh = *(const half8*)(Bsh + bbase + n * 128);
            half8 Bl = *(const half8*)(Bsl + bbase + n * 128);
            #pragma unroll
            for (int m = 0; m < 4; ++m)
                acc[m][n] = __builtin_amdgcn_mfma_f32_16x16x32_f16(Ah[m], Bh, acc[m][n], 0, 0, 0);
            #pragma unroll
            for (int m = 0; m < 4; ++m)
                acc[m][n] = __builtin_amdgcn_mfma_f32_16x16x32_f16(Ah[m], Bl, acc[m][n], 0, 0, 0);
            #pragma unroll
            for (int m = 0; m < 4; ++m)
                acc[m][n] = __builtin_amdgcn_mfma_f32_16x16x32_f16(Al[m], Bh, acc[m][n], 0, 0, 0);
        }
    }

    // epilogue: descale (exact 2^-16), bias, per-(row,chunk) max + expf-sum.
    // C/D layout: col = lane&15 (tx), row = kg*4 + reg. Transposed (coalesced) writes.
    const float S2 = 1.0f / 65536.0f;
    float bb[8];
    #pragma unroll
    for (int n = 0; n < 8; ++n) bb[n] = b2[vb + n * 16 + tx];
    #pragma unroll
    for (int m = 0; m < 4; ++m) {
        #pragma unroll
        for (int r = 0; r < 4; ++r) {
            float mxr = -__builtin_inff();
            float sr = 0.f;
            #pragma unroll
            for (int n = 0; n < 8; ++n) {
                float l = acc[m][n][r] * S2 + bb[n];
                mxr = fmaxf(mxr, l);
                sr += __expf(l);
            }
            #pragma unroll
            for (int off = 1; off < 16; off <<= 1) {
                mxr = fmaxf(mxr, __shfl_xor(mxr, off, 64));
                sr += __shfl_xor(sr, off, 64);
            }
            if (tx == 0) {
                int row = rbw + m * 16 + kg * 4 + r;
                cmT[(long)cb * B + row] = mxr;
                csT[(long)cb * B + row] = sr;
            }
        }
    }
}

// ---------------------------------------------------------------- tail finalize (t = T_STEPS-1), round-4 k_final
__global__ __launch_bounds__(256) void k_final(
    const float* __restrict__ cmT, const float* __restrict__ csT,
    const float* __restrict__ p32, const void* __restrict__ W2_raw,
    const float* __restrict__ b2, const float* __restrict__ wmax,
    int* __restrict__ it, int* __restrict__ unf,
    float* __restrict__ out, int t, const int* __restrict__ flag) {
    const bool isf = (*flag != 0);
    int r = blockIdx.x * 4 + (threadIdx.x >> 6);
    int lane = threadIdx.x & 63;
    const float* pr = p32 + (long)r * H;

    float pa = pr[lane], pb = pr[lane + 64];
    float pn2 = pa * pa + pb * pb;
    #pragma unroll
    for (int off = 1; off < 64; off <<= 1) pn2 += __shfl_xor(pn2, off, 64);
    float eps = 6.0e-5f * sqrtf(pn2) * (*wmax) + 3e-5f;

    float marr[4];
    float AM = -__builtin_inff();
    #pragma unroll
    for (int i = 0; i < 4; ++i) {
        int cc = lane + 64 * i;
        marr[i] = (cc < NCHUNK) ? cmT[(long)cc * B + r] : -__builtin_inff();
        AM = fmaxf(AM, marr[i]);
    }
    #pragma unroll
    for (int off = 1; off < 64; off <<= 1) AM = fmaxf(AM, __shfl_xor(AM, off, 64));
    double S = 0.0;
    #pragma unroll
    for (int i = 0; i < 4; ++i) {
        int cc = lane + 64 * i;
        if (cc < NCHUNK) S += (double)csT[(long)cc * B + r];
    }
    #pragma unroll
    for (int off = 1; off < 64; off <<= 1) S += __shfl_xor(S, off, 64);

    float M = -__builtin_inff();
    #pragma unroll 1
    for (int i = 0; i < 4; ++i) {
        unsigned long long mask = __ballot(marr[i] >= AM - eps);
        while (mask) {
            int b = __ffsll(mask) - 1;
            mask &= mask - 1;
            int cc = i * 64 + b;
            #pragma unroll
            for (int q = 0; q < 2; ++q) {
                int v = cc * 128 + q * 64 + lane;
                double acc = 0.0;
                if (isf) {
                    const float* wv = (const float*)W2_raw + (long)v * H;
                    for (int k = 0; k < H; ++k) acc += (double)pr[k] * (double)wv[k];
                } else {
                    const unsigned short* wv = (const unsigned short*)W2_raw + (long)v * H;
                    for (int k = 0; k < H; ++k) acc += (double)pr[k] * (double)bf2f(wv[k]);
                }
                float l = __fadd_rn((float)acc, b2[v]);
                M = fmaxf(M, l);
            }
        }
    }
    #pragma unroll
    for (int off = 1; off < 64; off <<= 1) M = fmaxf(M, __shfl_xor(M, off, 64));

    float L = (float)(log(S) - (double)M);
    float negL = __fsub_rn(0.0f, L);

    int best = INT_MAX;
    #pragma unroll 1
    for (int i = 0; i < 4 && best == INT_MAX; ++i) {
        unsigned long long mask = __ballot(marr[i] >= AM - eps);
        while (mask && best == INT_MAX) {
            int b = __ffsll(mask) - 1;
            mask &= mask - 1;
            int cc = i * 64 + b;
            int hit = INT_MAX;
            #pragma unroll
            for (int q = 0; q < 2; ++q) {
                int v = cc * 128 + q * 64 + lane;
                double acc = 0.0;
                if (isf) {
                    const float* wv = (const float*)W2_raw + (long)v * H;
                    for (int k = 0; k < H; ++k) acc += (double)pr[k] * (double)wv[k];
                } else {
                    const unsigned short* wv = (const unsigned short*)W2_raw + (long)v * H;
                    for (int k = 0; k < H; ++k) acc += (double)pr[k] * (double)bf2f(wv[k]);
                }
                float l  = __fadd_rn((float)acc, b2[v]);
                float lp = __fsub_rn(__fsub_rn(l, M), L);
                if (lp == negL && v < hit) hit = v;
            }
            #pragma unroll
            for (int off = 1; off < 64; off <<= 1) {
                int oh = __shfl_xor(hit, off, 64);
                hit = (oh < hit) ? oh : hit;
            }
            if (hit != INT_MAX) best = hit;
        }
    }
    int bi = (best == INT_MAX) ? 0 : best;

    int unfr = unf[r];
    float lp = negL;
    int itn = unfr ? bi : 0;
    int unfn = (unfr && itn != EOS) ? 1 : 0;
    if (lane == 0) { it[r] = itn; unf[r] = unfn; }
    if (lane < NS) {
        long ro = (long)r * NS + lane;
        out[ro * T_STEPS + t] = (float)itn;
        out[(long)BFULL * T_STEPS + ro * T_STEPS + t] = lp;
        out[2L * BFULL * T_STEPS + ro * T_STEPS + t] = unfr ? 1.0f : 0.0f;
    }
}

// ---------------------------------------------------------------- launch
extern "C" void kernel_launch(void* const* d_in, const int* in_sizes, int n_in,
                              void* d_out, int out_size, void* d_ws, size_t ws_size,
                              hipStream_t stream) {
    float* out = (float*)d_out;

    char* w = (char*)d_ws;
    float* fin[12];
    for (int i = 0; i < 12; ++i) {
        if (i == 1 || i == 10) { fin[i] = nullptr; continue; }   // embed/W2 read raw
        fin[i] = (float*)w;
        size_t bytes = ((size_t)in_sizes[i] * 4 + 15) & ~(size_t)15;
        w += bytes;
    }
    float*  h     = (float*) w; w += (size_t)B * H * 4;
    float*  c     = (float*) w; w += (size_t)B * H * 4;
    float*  p32   = (float*) w; w += (size_t)B * H * 4;
    float*  cm    = (float*) w; w += (size_t)B * NCHUNK * 4;
    float*  cs    = (float*) w; w += (size_t)B * NCHUNK * 4;
    float*  wn    = (float*) w; w += (size_t)V * 4;
    float*  wmax  = (float*) w; w += 16;
    int*    it    = (int*)   w; w += (size_t)B * 4;
    int*    unf   = (int*)   w; w += (size_t)B * 4;
    int*    flag  = (int*)   w; w += 16;
    unsigned short* ph = (unsigned short*)w; w += (size_t)B * H * 2;
    unsigned short* pl = (unsigned short*)w; w += (size_t)B * H * 2;
    unsigned short* wh = (unsigned short*)w; w += (size_t)V * H * 2;
    unsigned short* wl = (unsigned short*)w; w += (size_t)V * H * 2;

    k_detect<<<1, 64, 0, stream>>>((const unsigned short*)d_in[1], flag);

    // one dispatch for all transcodes
    TCArgs tc;
    int maxn = 0;
    for (int i = 0; i < 12; ++i) {
        tc.src[i] = d_in[i];
        tc.dst[i] = fin[i];
        tc.n[i]   = in_sizes[i];
        if (fin[i] && in_sizes[i] > maxn) maxn = in_sizes[i];
    }
    k_transcode_all<<<dim3((maxn + 255) / 256, 12), 256, 0, stream>>>(tc, flag);

    k_wsplit<<<(V * H / 8 + 255) / 256, 256, 0, stream>>>(d_in[10], wh, wl, wn, flag);
    k_prep<<<5, 256, 0, stream>>>(wn, wmax, it, unf);

    const float* xf  = fin[0];
    const float* Wfc = fin[2];
    const float* bfc = fin[3];
    const float* Wih = fin[4];
    const float* bih = fin[5];
    const float* Whh = fin[6];
    const float* bhh = fin[7];
    const float* W1  = fin[8];
    const float* b1  = fin[9];
    const float* b2  = fin[11];

    k_init_hc<<<B, 256, 0, stream>>>(xf, Wfc, bfc, h, c);

    for (int t = 0; t < T_STEPS; ++t) {
        k_gf<<<B / 4, 256, 0, stream>>>(cm, cs, d_in[10], b2, wmax,
                                        d_in[1], h, c, Wih, Whh, bih, bhh,
                                        W1, b1, p32, ph, pl, it, unf, out, t, flag);
        k_vscan_mfma<<<1024, 256, 0, stream>>>(ph, pl, wh, wl, b2, cm, cs);
    }
    k_final<<<B / 4, 256, 0, stream>>>(cm, cs, p32, d_in[10], b2, wmax, it, unf, out,
                                       T_STEPS - 1, flag);
}

// Round 7
// 2112.998 us; speedup vs baseline: 1.5368x; 1.0374x over previous
//
#include <hip/hip_runtime.h>
#include <math.h>
#include <limits.h>

#define H 128
#define V 32000
#define CD 256
#define T_STEPS 21
#define NS 5
#define SOS 1
#define EOS 2
#define B 1024          // unique rows; reference B=5120 is 5 identical copies of each
#define BFULL 5120
#define NCHUNK 250      // V / 128

typedef _Float16 f16;
typedef f16   half8   __attribute__((ext_vector_type(8)));
typedef float floatx4 __attribute__((ext_vector_type(4)));
typedef unsigned short ushort8v __attribute__((ext_vector_type(8)));

#define AS1 __attribute__((address_space(1)))
#define AS3 __attribute__((address_space(3)))

__device__ __forceinline__ float bf2f(unsigned short u) {
    return __uint_as_float(((unsigned)u) << 16);
}

// np-faithful f32 sigmoid/tanh: f64 interior, single f32 round per np op.
__device__ __forceinline__ float sig32(float x) {
    float t = (float)exp(-(double)x);
    float r = __fadd_rn(1.0f, t);
    return __fdiv_rn(1.0f, r);
}
__device__ __forceinline__ float tanh32(float x) { return (float)tanh((double)x); }

// exact f64-recipe dot of p-row (f32, global) with W2 row v, k ascending.
// Vectorized loads (float4/ushort4); the f64 add order is identical to the
// scalar loop, so the result is bit-identical.
__device__ __forceinline__ double w2dot(const float* __restrict__ pr,
                                        const void* __restrict__ W2_raw,
                                        int v, bool isf) {
    double acc = 0.0;
    if (isf) {
        const float* wv = (const float*)W2_raw + (long)v * H;
        #pragma unroll 8
        for (int k4 = 0; k4 < H / 4; ++k4) {
            float4 wq = *(const float4*)(wv + k4 * 4);
            float4 pq = *(const float4*)(pr + k4 * 4);
            acc += (double)pq.x * (double)wq.x;
            acc += (double)pq.y * (double)wq.y;
            acc += (double)pq.z * (double)wq.z;
            acc += (double)pq.w * (double)wq.w;
        }
    } else {
        const unsigned short* wv = (const unsigned short*)W2_raw + (long)v * H;
        #pragma unroll 8
        for (int k4 = 0; k4 < H / 4; ++k4) {
            ushort4 u = *(const ushort4*)(wv + k4 * 4);
            float4 pq = *(const float4*)(pr + k4 * 4);
            acc += (double)pq.x * (double)bf2f(u.x);
            acc += (double)pq.y * (double)bf2f(u.y);
            acc += (double)pq.z * (double)bf2f(u.z);
            acc += (double)pq.w * (double)bf2f(u.w);
        }
    }
    return acc;
}

// ---------------------------------------------------------------- input dtype sniffer
__global__ void k_detect(const unsigned short* __restrict__ e, int* __restrict__ flag) {
    int i = threadIdx.x;
    unsigned short u = e[2 * i];
    int ex = (u >> 7) & 0xFF;
    bool wild = ((u & 0x7FFF) != 0) && (ex < 0x60 || ex > 0x8F);
    unsigned long long m = __ballot(wild);
    if (i == 0) *flag = (m != 0ull) ? 1 : 0;   // 1 = f32 inputs, 0 = bf16
}

// ---------------------------------------------------------------- transcode ALL f32-bound inputs in one dispatch
struct TCArgs {
    const void* src[12];
    float*      dst[12];
    int         n[12];
};
__global__ __launch_bounds__(256) void k_transcode_all(TCArgs tc, const int* __restrict__ flag) {
    int which = blockIdx.y;
    float* d = tc.dst[which];
    if (d == nullptr) return;
    int i = blockIdx.x * 256 + threadIdx.x;
    if (i >= tc.n[which]) return;
    if (*flag) d[i] = ((const float*)tc.src[which])[i];
    else       d[i] = bf2f(((const unsigned short*)tc.src[which])[i]);
}

// ---------------------------------------------------------------- W2: coalesced norm + scaled f16 hi/lo split (once per launch)
// Emits wh/wl in FRAGMENT-MAJOR order: f16 index = cb*16384 + kkg*1024 + row_local*8 + j
// (cb = vrow/128, row_local = vrow%128, kkg = k/8) — the exact LDS layout
// k_vscan_mfma consumes, so staging is a linear copy.
__global__ __launch_bounds__(256) void k_wsplit(
    const void* __restrict__ W2_raw, unsigned short* __restrict__ wh,
    unsigned short* __restrict__ wl, float* __restrict__ wn,
    const int* __restrict__ flag) {
    int t = blockIdx.x * 256 + threadIdx.x;       // t in [0, V*H/8)
    const bool isf = (*flag != 0);
    int vrow = t >> 4;                            // vocab row
    int kkg  = t & 15;                            // which 8-wide k group
    float v[8];
    if (isf) {
        float4 f0 = ((const float4*)W2_raw)[2 * t];
        float4 f1 = ((const float4*)W2_raw)[2 * t + 1];
        v[0] = f0.x; v[1] = f0.y; v[2] = f0.z; v[3] = f0.w;
        v[4] = f1.x; v[5] = f1.y; v[6] = f1.z; v[7] = f1.w;
    } else {
        ushort8v u = ((const ushort8v*)W2_raw)[t];
        #pragma unroll
        for (int i = 0; i < 8; ++i) v[i] = bf2f(u[i]);
    }
    float s = 0.f;
    half8 hv, lv;
    #pragma unroll
    for (int i = 0; i < 8; ++i) {
        s += v[i] * v[i];
        float ws = v[i] * 256.0f;
        f16 hh = (f16)ws;
        hv[i] = hh;
        lv[i] = (f16)(ws - (float)hh);
    }
    int cb = vrow >> 7, rloc = vrow & 127;
    long dst = (long)cb * 16384 + kkg * 1024 + rloc * 8;
    *(half8*)((f16*)wh + dst) = hv;
    *(half8*)((f16*)wl + dst) = lv;
    // row norm: 16 consecutive threads share a row
    #pragma unroll
    for (int off = 1; off < 16; off <<= 1) s += __shfl_xor(s, off, 64);
    if (kkg == 0) wn[vrow] = sqrtf(s);
}

// ---------------------------------------------------------------- prep: wmax (block 4) + it/unf init (blocks 0-3)
__global__ __launch_bounds__(256) void k_prep(
    const float* __restrict__ wn, float* __restrict__ wmax,
    int* __restrict__ it, int* __restrict__ unf) {
    int tid = threadIdx.x;
    if (blockIdx.x < 4) {
        int i = blockIdx.x * 256 + tid;
        it[i] = SOS; unf[i] = 1;
        return;
    }
    __shared__ float red[4];
    float m = 0.f;
    for (int i = tid; i < V; i += 256) m = fmaxf(m, wn[i]);
    #pragma unroll
    for (int off = 1; off < 64; off <<= 1) m = fmaxf(m, __shfl_xor(m, off, 64));
    if ((tid & 63) == 0) red[tid >> 6] = m;
    __syncthreads();
    if (tid == 0) *wmax = fmaxf(fmaxf(red[0], red[1]), fmaxf(red[2], red[3]));
}

// ---------------------------------------------------------------- hc = fl32(x @ W_fc.T) + b_fc
__global__ __launch_bounds__(256) void k_init_hc(
    const float* __restrict__ xf, const float* __restrict__ Wfc,
    const float* __restrict__ bfc, float* __restrict__ h, float* __restrict__ c) {
    __shared__ float xl[CD];
    int r = blockIdx.x;
    int j = threadIdx.x;
    xl[j] = xf[(long)r * CD + j];
    __syncthreads();
    const float4* w4 = (const float4*)(Wfc + (long)j * CD);
    double acc = 0.0;
    for (int k4 = 0; k4 < CD / 4; ++k4) {
        float4 w = w4[k4];
        int k = k4 * 4;
        acc += (double)xl[k]     * (double)w.x;
        acc += (double)xl[k + 1] * (double)w.y;
        acc += (double)xl[k + 2] * (double)w.z;
        acc += (double)xl[k + 3] * (double)w.w;
    }
    float hc = __fadd_rn((float)acc, bfc[j]);
    if (j < H) h[(long)r * H + j] = hc;
    else       c[(long)r * H + (j - H)] = hc;
}

// ---------------------------------------------------------------- fused F(t-1) + G(t), 512 threads (8 waves/CU):
// 256 blocks, rows rb..rb+3 owned end-to-end.
// Phase F (t>0, waves 0-3): norm-bounded candidate rescue for step t-1 using
//   cm/cs from the previous V dispatch (launch boundary = global sync).
//   Vectorized W2 loads; f64 add order unchanged (bit-identical).
// Phase G (all 8 waves): gates = 1 column/thread x 4 row-accumulators;
//   cell = 1 elem/thread; proj = (row,col)/thread. Per-output f64 chains in
//   identical k-ascending order -> bit-identical gates/h/c/p32.
__global__ __launch_bounds__(512) void k_gf(
    const float* __restrict__ cmT, const float* __restrict__ csT,
    const void* __restrict__ W2_raw, const float* __restrict__ b2,
    const float* __restrict__ wmax,
    const void* __restrict__ embed_raw, float* __restrict__ h, float* __restrict__ c,
    const float* __restrict__ Wih, const float* __restrict__ Whh,
    const float* __restrict__ bih, const float* __restrict__ bhh,
    const float* __restrict__ W1, const float* __restrict__ b1,
    float* __restrict__ p32, unsigned short* __restrict__ ph,
    unsigned short* __restrict__ pl,
    int* __restrict__ it, int* __restrict__ unf, float* __restrict__ out,
    int t, const int* __restrict__ flag) {
    __shared__ float As[4][256];    // concat(e_tok, h) per row
    __shared__ float gsh[4][512];   // gates
    __shared__ float hl[4][132];
    const bool isf = (*flag != 0);
    int tid = threadIdx.x;
    int rb = blockIdx.x * 4;
    int lane = tid & 63, wid = tid >> 6;

    // ================= F: finalize step t-1 for row rb+wid (waves 0-3) =================
    if (t > 0 && wid < 4) {
        int r = rb + wid;
        const float* pr = p32 + (long)r * H;

        float pa = pr[lane], pb = pr[lane + 64];
        float pn2 = pa * pa + pb * pb;
        #pragma unroll
        for (int off = 1; off < 64; off <<= 1) pn2 += __shfl_xor(pn2, off, 64);
        // rigorous window for the split-f16 MFMA scan
        float eps = 6.0e-5f * sqrtf(pn2) * (*wmax) + 3e-5f;

        float marr[4];
        float AM = -__builtin_inff();
        #pragma unroll
        for (int i = 0; i < 4; ++i) {
            int cc = lane + 64 * i;
            marr[i] = (cc < NCHUNK) ? cmT[(long)cc * B + r] : -__builtin_inff();
            AM = fmaxf(AM, marr[i]);
        }
        #pragma unroll
        for (int off = 1; off < 64; off <<= 1) AM = fmaxf(AM, __shfl_xor(AM, off, 64));
        double S = 0.0;
        #pragma unroll
        for (int i = 0; i < 4; ++i) {
            int cc = lane + 64 * i;
            if (cc < NCHUNK) S += (double)csT[(long)cc * B + r];
        }
        #pragma unroll
        for (int off = 1; off < 64; off <<= 1) S += __shfl_xor(S, off, 64);

        // pass A: exact f64-recipe max over candidate chunks
        float M = -__builtin_inff();
        #pragma unroll 1
        for (int i = 0; i < 4; ++i) {
            unsigned long long mask = __ballot(marr[i] >= AM - eps);
            while (mask) {
                int bsl = __ffsll(mask) - 1;
                mask &= mask - 1;
                int cc = i * 64 + bsl;
                #pragma unroll
                for (int q = 0; q < 2; ++q) {
                    int v = cc * 128 + q * 64 + lane;
                    double acc = w2dot(pr, W2_raw, v, isf);
                    float l = __fadd_rn((float)acc, b2[v]);
                    M = fmaxf(M, l);
                }
            }
        }
        #pragma unroll
        for (int off = 1; off < 64; off <<= 1) M = fmaxf(M, __shfl_xor(M, off, 64));

        float L = (float)(log(S) - (double)M);
        float negL = __fsub_rn(0.0f, L);

        // pass B: first v whose f32 logprob equals -L
        int best = INT_MAX;
        #pragma unroll 1
        for (int i = 0; i < 4 && best == INT_MAX; ++i) {
            unsigned long long mask = __ballot(marr[i] >= AM - eps);
            while (mask && best == INT_MAX) {
                int bsl = __ffsll(mask) - 1;
                mask &= mask - 1;
                int cc = i * 64 + bsl;
                int hit = INT_MAX;
                #pragma unroll
                for (int q = 0; q < 2; ++q) {
                    int v = cc * 128 + q * 64 + lane;
                    double acc = w2dot(pr, W2_raw, v, isf);
                    float l  = __fadd_rn((float)acc, b2[v]);
                    float lp = __fsub_rn(__fsub_rn(l, M), L);
                    if (lp == negL && v < hit) hit = v;
                }
                #pragma unroll
                for (int off = 1; off < 64; off <<= 1) {
                    int oh = __shfl_xor(hit, off, 64);
                    hit = (oh < hit) ? oh : hit;
                }
                if (hit != INT_MAX) best = hit;
            }
        }
        int bi = (best == INT_MAX) ? 0 : best;

        int unfr = unf[r];
        float lp = negL;
        int itn = unfr ? bi : 0;
        int unfn = (unfr && itn != EOS) ? 1 : 0;
        if (lane == 0) { it[r] = itn; unf[r] = unfn; }
        if (lane < NS) {
            long ro = (long)r * NS + lane;
            int tm1 = t - 1;
            out[ro * T_STEPS + tm1] = (float)itn;
            out[(long)BFULL * T_STEPS + ro * T_STEPS + tm1] = lp;
            out[2L * BFULL * T_STEPS + ro * T_STEPS + tm1] = unfr ? 1.0f : 0.0f;
        }
    }
    __syncthreads();

    // ================= G: gates + cell + proj (rows rb..rb+3) =================
    {   // stage As: thread -> row (tid>>7), 2 consecutive elems
        int r = tid >> 7, kq = (tid & 127) * 2;
        long row = rb + r;
        int tok = it[row];
        float v0, v1;
        if (kq < H) {
            if (isf) {
                float2 f = *(const float2*)((const float*)embed_raw + (long)tok * H + kq);
                v0 = f.x; v1 = f.y;
            } else {
                ushort2 u = *(const ushort2*)((const unsigned short*)embed_raw + (long)tok * H + kq);
                v0 = bf2f(u.x); v1 = bf2f(u.y);
            }
        } else {
            float2 f = *(const float2*)(h + row * H + (kq - H));
            v0 = f.x; v1 = f.y;
        }
        As[r][kq] = v0; As[r][kq + 1] = v1;
    }
    __syncthreads();

    {   // gates: thread owns ONE gate column cg = tid; 4 rows
        int cg = tid;
        double acc[4] = {};
        const float* wi = Wih + (long)cg * H;
        for (int k4 = 0; k4 < H / 4; ++k4) {
            float4 w = *(const float4*)(wi + k4 * 4);
            int k = k4 * 4;
            #pragma unroll
            for (int r = 0; r < 4; ++r) {
                double s0 = acc[r];
                float4 a = *(const float4*)(&As[r][k]);   // broadcast read
                s0 += (double)a.x * (double)w.x;
                s0 += (double)a.y * (double)w.y;
                s0 += (double)a.z * (double)w.z;
                s0 += (double)a.w * (double)w.w;
                acc[r] = s0;
            }
        }
        float t1[4];
        float bi = bih[cg];
        #pragma unroll
        for (int r = 0; r < 4; ++r) {
            t1[r] = __fadd_rn((float)acc[r], bi);
            acc[r] = 0.0;
        }
        const float* wh = Whh + (long)cg * H;
        for (int k4 = 0; k4 < H / 4; ++k4) {
            float4 w = *(const float4*)(wh + k4 * 4);
            int k = H + k4 * 4;
            #pragma unroll
            for (int r = 0; r < 4; ++r) {
                double s0 = acc[r];
                float4 a = *(const float4*)(&As[r][k]);
                s0 += (double)a.x * (double)w.x;
                s0 += (double)a.y * (double)w.y;
                s0 += (double)a.z * (double)w.z;
                s0 += (double)a.w * (double)w.w;
                acc[r] = s0;
            }
        }
        float bh = bhh[cg];
        #pragma unroll
        for (int r = 0; r < 4; ++r)
            gsh[r][cg] = __fadd_rn(__fadd_rn(t1[r], (float)acc[r]), bh);
    }
    __syncthreads();

    {   // cell: one element per thread (4 rows x 128)
        int lr = tid >> 7, j = tid & 127;
        long row = rb + lr;
        float gi = gsh[lr][j], gf = gsh[lr][j + 128], gg = gsh[lr][j + 256], go = gsh[lr][j + 384];
        float cv = c[row * 128 + j];
        float si = sig32(gi);
        float sf = sig32(gf);
        float so = sig32(go);
        float tg = tanh32(gg);
        float cn = __fadd_rn(__fmul_rn(sf, cv), __fmul_rn(si, tg));
        float hn = __fmul_rn(so, tanh32(cn));
        c[row * 128 + j] = cn;
        h[row * 128 + j] = hn;
        hl[lr][j] = hn;
    }
    __syncthreads();

    {   // proj + p-split: thread -> (row tid>>7, col tid&127)
        int j = tid & 127;
        int rr = tid >> 7;
        const float4* w4 = (const float4*)(W1 + (long)j * H);
        double acc = 0.0;
        for (int k4 = 0; k4 < H / 4; ++k4) {
            float4 w = w4[k4];
            int k = k4 * 4;
            acc += (double)hl[rr][k]     * (double)w.x;
            acc += (double)hl[rr][k + 1] * (double)w.y;
            acc += (double)hl[rr][k + 2] * (double)w.z;
            acc += (double)hl[rr][k + 3] * (double)w.w;
        }
        long row = rb + rr;
        float pv = __fadd_rn((float)acc, b1[j]);
        p32[row * H + j] = pv;
        float ps = pv * 256.0f;
        f16 hh = (f16)ps;
        f16 ll = (f16)(ps - (float)hh);
        ((f16*)ph)[row * H + j] = hh;
        ((f16*)pl)[row * H + j] = ll;
    }
}

// ---------------------------------------------------------------- vocab scan via split-f16 MFMA (round-4 version, unchanged):
// 1024 blocks x 256 thr, 4 waves, 2 blocks/CU, XCD-grouped swizzle,
// transposed cm/cs [cb][row] (coalesced writes), global_load_lds staging.
__global__ __launch_bounds__(256, 2) void k_vscan_mfma(
    const unsigned short* __restrict__ ph_, const unsigned short* __restrict__ pl_,
    const unsigned short* __restrict__ whf_, const unsigned short* __restrict__ wlf_,
    const float* __restrict__ b2, float* __restrict__ cmT, float* __restrict__ csT) {
    __shared__ f16 Bsh[16384];   // 32 KB
    __shared__ f16 Bsl[16384];   // 32 KB
    const f16* ph  = (const f16*)ph_;
    const f16* pl  = (const f16*)pl_;
    int tid  = threadIdx.x;
    int lane = tid & 63, wid = tid >> 6;
    int tx = lane & 15, kg = lane >> 4;

    // bid = hi*32 + rb*8 + xcd  ->  cb = hi*8 + xcd  (same cb -> same bid%8 -> same XCD)
    int bid = blockIdx.x;
    int xcd = bid & 7, rb = (bid >> 3) & 3, hi = bid >> 5;
    int cb = hi * 8 + xcd;
    if (cb >= NCHUNK) return;
    int rbw = rb * 256 + wid * 64;
    int vb  = cb * 128;

    // stage B tile: linear 64KB direct-to-LDS (global fragment-major == LDS layout)
    {
        const f16* sh = (const f16*)whf_ + (long)cb * 16384;
        const f16* sl = (const f16*)wlf_ + (long)cb * 16384;
        #pragma unroll
        for (int i = 0; i < 8; ++i) {
            int g = tid + 256 * i;               // 16B chunk id, 0..2047
            __builtin_amdgcn_global_load_lds(
                (const AS1 void*)(const void*)(sh + (long)g * 8),
                (AS3 void*)(void*)(Bsh + g * 8), 16, 0, 0);
            __builtin_amdgcn_global_load_lds(
                (const AS1 void*)(const void*)(sl + (long)g * 8),
                (AS3 void*)(void*)(Bsl + g * 8), 16, 0, 0);
        }
    }
    __syncthreads();

    floatx4 acc[4][8];
    #pragma unroll
    for (int m = 0; m < 4; ++m)
        #pragma unroll
        for (int n = 0; n < 8; ++n)
            acc[m][n] = (floatx4){0.f, 0.f, 0.f, 0.f};

    int aoffs[4];
    #pragma unroll
    for (int m = 0; m < 4; ++m) aoffs[m] = (rbw + m * 16 + tx) * H + kg * 8;

    #pragma unroll
    for (int kk = 0; kk < 4; ++kk) {
        half8 Ah[4], Al[4];
        #pragma unroll
        for (int m = 0; m < 4; ++m) {
            Ah[m] = *(const half8*)(ph + aoffs[m] + kk * 32);
            Al[m] = *(const half8*)(pl + aoffs[m] + kk * 32);
        }
        int bbase = (kk * 4 + kg) * 1024 + tx * 8;
        #pragma unroll
        for (int n = 0; n < 8; ++n) {
            half8 Bh = *(const half8*)(Bsh + bbase + n * 128);
            half8 Bl = *(const half8*)(Bsl + bbase + n * 128);
            #pragma unroll
            for (int m = 0; m < 4; ++m)
                acc[m][n] = __builtin_amdgcn_mfma_f32_16x16x32_f16(Ah[m], Bh, acc[m][n], 0, 0, 0);
            #pragma unroll
            for (int m = 0; m < 4; ++m)
                acc[m][n] = __builtin_amdgcn_mfma_f32_16x16x32_f16(Ah[m], Bl, acc[m][n], 0, 0, 0);
            #pragma unroll
            for (int m = 0; m < 4; ++m)
                acc[m][n] = __builtin_amdgcn_mfma_f32_16x16x32_f16(Al[m], Bh, acc[m][n], 0, 0, 0);
        }
    }

    // epilogue: descale (exact 2^-16), bias, per-(row,chunk) max + expf-sum.
    // C/D layout: col = lane&15 (tx), row = kg*4 + reg. Transposed (coalesced) writes.
    const float S2 = 1.0f / 65536.0f;
    float bb[8];
    #pragma unroll
    for (int n = 0; n < 8; ++n) bb[n] = b2[vb + n * 16 + tx];
    #pragma unroll
    for (int m = 0; m < 4; ++m) {
        #pragma unroll
        for (int r = 0; r < 4; ++r) {
            float mxr = -__builtin_inff();
            float sr = 0.f;
            #pragma unroll
            for (int n = 0; n < 8; ++n) {
                float l = acc[m][n][r] * S2 + bb[n];
                mxr = fmaxf(mxr, l);
                sr += __expf(l);
            }
            #pragma unroll
            for (int off = 1; off < 16; off <<= 1) {
                mxr = fmaxf(mxr, __shfl_xor(mxr, off, 64));
                sr += __shfl_xor(sr, off, 64);
            }
            if (tx == 0) {
                int row = rbw + m * 16 + kg * 4 + r;
                cmT[(long)cb * B + row] = mxr;
                csT[(long)cb * B + row] = sr;
            }
        }
    }
}

// ---------------------------------------------------------------- tail finalize (t = T_STEPS-1)
__global__ __launch_bounds__(256) void k_final(
    const float* __restrict__ cmT, const float* __restrict__ csT,
    const float* __restrict__ p32, const void* __restrict__ W2_raw,
    const float* __restrict__ b2, const float* __restrict__ wmax,
    int* __restrict__ it, int* __restrict__ unf,
    float* __restrict__ out, int t, const int* __restrict__ flag) {
    const bool isf = (*flag != 0);
    int r = blockIdx.x * 4 + (threadIdx.x >> 6);
    int lane = threadIdx.x & 63;
    const float* pr = p32 + (long)r * H;

    float pa = pr[lane], pb = pr[lane + 64];
    float pn2 = pa * pa + pb * pb;
    #pragma unroll
    for (int off = 1; off < 64; off <<= 1) pn2 += __shfl_xor(pn2, off, 64);
    float eps = 6.0e-5f * sqrtf(pn2) * (*wmax) + 3e-5f;

    float marr[4];
    float AM = -__builtin_inff();
    #pragma unroll
    for (int i = 0; i < 4; ++i) {
        int cc = lane + 64 * i;
        marr[i] = (cc < NCHUNK) ? cmT[(long)cc * B + r] : -__builtin_inff();
        AM = fmaxf(AM, marr[i]);
    }
    #pragma unroll
    for (int off = 1; off < 64; off <<= 1) AM = fmaxf(AM, __shfl_xor(AM, off, 64));
    double S = 0.0;
    #pragma unroll
    for (int i = 0; i < 4; ++i) {
        int cc = lane + 64 * i;
        if (cc < NCHUNK) S += (double)csT[(long)cc * B + r];
    }
    #pragma unroll
    for (int off = 1; off < 64; off <<= 1) S += __shfl_xor(S, off, 64);

    float M = -__builtin_inff();
    #pragma unroll 1
    for (int i = 0; i < 4; ++i) {
        unsigned long long mask = __ballot(marr[i] >= AM - eps);
        while (mask) {
            int b = __ffsll(mask) - 1;
            mask &= mask - 1;
            int cc = i * 64 + b;
            #pragma unroll
            for (int q = 0; q < 2; ++q) {
                int v = cc * 128 + q * 64 + lane;
                double acc = w2dot(pr, W2_raw, v, isf);
                float l = __fadd_rn((float)acc, b2[v]);
                M = fmaxf(M, l);
            }
        }
    }
    #pragma unroll
    for (int off = 1; off < 64; off <<= 1) M = fmaxf(M, __shfl_xor(M, off, 64));

    float L = (float)(log(S) - (double)M);
    float negL = __fsub_rn(0.0f, L);

    int best = INT_MAX;
    #pragma unroll 1
    for (int i = 0; i < 4 && best == INT_MAX; ++i) {
        unsigned long long mask = __ballot(marr[i] >= AM - eps);
        while (mask && best == INT_MAX) {
            int b = __ffsll(mask) - 1;
            mask &= mask - 1;
            int cc = i * 64 + b;
            int hit = INT_MAX;
            #pragma unroll
            for (int q = 0; q < 2; ++q) {
                int v = cc * 128 + q * 64 + lane;
                double acc = w2dot(pr, W2_raw, v, isf);
                float l  = __fadd_rn((float)acc, b2[v]);
                float lp = __fsub_rn(__fsub_rn(l, M), L);
                if (lp == negL && v < hit) hit = v;
            }
            #pragma unroll
            for (int off = 1; off < 64; off <<= 1) {
                int oh = __shfl_xor(hit, off, 64);
                hit = (oh < hit) ? oh : hit;
            }
            if (hit != INT_MAX) best = hit;
        }
    }
    int bi = (best == INT_MAX) ? 0 : best;

    int unfr = unf[r];
    float lp = negL;
    int itn = unfr ? bi : 0;
    int unfn = (unfr && itn != EOS) ? 1 : 0;
    if (lane == 0) { it[r] = itn; unf[r] = unfn; }
    if (lane < NS) {
        long ro = (long)r * NS + lane;
        out[ro * T_STEPS + t] = (float)itn;
        out[(long)BFULL * T_STEPS + ro * T_STEPS + t] = lp;
        out[2L * BFULL * T_STEPS + ro * T_STEPS + t] = unfr ? 1.0f : 0.0f;
    }
}

// ---------------------------------------------------------------- launch
extern "C" void kernel_launch(void* const* d_in, const int* in_sizes, int n_in,
                              void* d_out, int out_size, void* d_ws, size_t ws_size,
                              hipStream_t stream) {
    float* out = (float*)d_out;

    char* w = (char*)d_ws;
    float* fin[12];
    for (int i = 0; i < 12; ++i) {
        if (i == 1 || i == 10) { fin[i] = nullptr; continue; }   // embed/W2 read raw
        fin[i] = (float*)w;
        size_t bytes = ((size_t)in_sizes[i] * 4 + 15) & ~(size_t)15;
        w += bytes;
    }
    float*  h     = (float*) w; w += (size_t)B * H * 4;
    float*  c     = (float*) w; w += (size_t)B * H * 4;
    float*  p32   = (float*) w; w += (size_t)B * H * 4;
    float*  cm    = (float*) w; w += (size_t)B * NCHUNK * 4;
    float*  cs    = (float*) w; w += (size_t)B * NCHUNK * 4;
    float*  wn    = (float*) w; w += (size_t)V * 4;
    float*  wmax  = (float*) w; w += 16;
    int*    it    = (int*)   w; w += (size_t)B * 4;
    int*    unf   = (int*)   w; w += (size_t)B * 4;
    int*    flag  = (int*)   w; w += 16;
    unsigned short* ph = (unsigned short*)w; w += (size_t)B * H * 2;
    unsigned short* pl = (unsigned short*)w; w += (size_t)B * H * 2;
    unsigned short* wh = (unsigned short*)w; w += (size_t)V * H * 2;
    unsigned short* wl = (unsigned short*)w; w += (size_t)V * H * 2;

    k_detect<<<1, 64, 0, stream>>>((const unsigned short*)d_in[1], flag);

    // one dispatch for all transcodes
    TCArgs tc;
    int maxn = 0;
    for (int i = 0; i < 12; ++i) {
        tc.src[i] = d_in[i];
        tc.dst[i] = fin[i];
        tc.n[i]   = in_sizes[i];
        if (fin[i] && in_sizes[i] > maxn) maxn = in_sizes[i];
    }
    k_transcode_all<<<dim3((maxn + 255) / 256, 12), 256, 0, stream>>>(tc, flag);

    k_wsplit<<<(V * H / 8 + 255) / 256, 256, 0, stream>>>(d_in[10], wh, wl, wn, flag);
    k_prep<<<5, 256, 0, stream>>>(wn, wmax, it, unf);

    const float* xf  = fin[0];
    const float* Wfc = fin[2];
    const float* bfc = fin[3];
    const float* Wih = fin[4];
    const float* bih = fin[5];
    const float* Whh = fin[6];
    const float* bhh = fin[7];
    const float* W1  = fin[8];
    const float* b1  = fin[9];
    const float* b2  = fin[11];

    k_init_hc<<<B, 256, 0, stream>>>(xf, Wfc, bfc, h, c);

    for (int t = 0; t < T_STEPS; ++t) {
        k_gf<<<B / 4, 512, 0, stream>>>(cm, cs, d_in[10], b2, wmax,
                                        d_in[1], h, c, Wih, Whh, bih, bhh,
                                        W1, b1, p32, ph, pl, it, unf, out, t, flag);
        k_vscan_mfma<<<1024, 256, 0, stream>>>(ph, pl, wh, wl, b2, cm, cs);
    }
    k_final<<<B / 4, 256, 0, stream>>>(cm, cs, p32, d_in[10], b2, wmax, it, unf, out,
                                       T_STEPS - 1, flag);
}

// Round 8
// 1833.935 us; speedup vs baseline: 1.7706x; 1.1522x over previous
//
#include <hip/hip_runtime.h>
#include <math.h>
#include <limits.h>

#define H 128
#define V 32000
#define CD 256
#define T_STEPS 21
#define NS 5
#define SOS 1
#define EOS 2
#define B 1024          // unique rows; reference B=5120 is 5 identical copies of each
#define BFULL 5120
#define NCHUNK 250      // V / 128

typedef _Float16 f16;
typedef f16   half8   __attribute__((ext_vector_type(8)));
typedef float floatx4 __attribute__((ext_vector_type(4)));
typedef unsigned short ushort8v __attribute__((ext_vector_type(8)));

#define AS1 __attribute__((address_space(1)))
#define AS3 __attribute__((address_space(3)))

__device__ __forceinline__ float bf2f(unsigned short u) {
    return __uint_as_float(((unsigned)u) << 16);
}

// np-faithful f32 sigmoid/tanh: f64 interior, single f32 round per np op.
__device__ __forceinline__ float sig32(float x) {
    float t = (float)exp(-(double)x);
    float r = __fadd_rn(1.0f, t);
    return __fdiv_rn(1.0f, r);
}
__device__ __forceinline__ float tanh32(float x) { return (float)tanh((double)x); }

// exact f64-recipe dot of p-row (f32, global) with W2 row v, k ascending.
// Vectorized loads; the f64 add order is identical to the scalar loop, so the
// result is bit-identical.
__device__ __forceinline__ double w2dot(const float* __restrict__ pr,
                                        const void* __restrict__ W2_raw,
                                        int v, bool isf) {
    double acc = 0.0;
    if (isf) {
        const float* wv = (const float*)W2_raw + (long)v * H;
        #pragma unroll 8
        for (int k4 = 0; k4 < H / 4; ++k4) {
            float4 wq = *(const float4*)(wv + k4 * 4);
            float4 pq = *(const float4*)(pr + k4 * 4);
            acc += (double)pq.x * (double)wq.x;
            acc += (double)pq.y * (double)wq.y;
            acc += (double)pq.z * (double)wq.z;
            acc += (double)pq.w * (double)wq.w;
        }
    } else {
        const unsigned short* wv = (const unsigned short*)W2_raw + (long)v * H;
        #pragma unroll 8
        for (int k4 = 0; k4 < H / 4; ++k4) {
            ushort4 u = *(const ushort4*)(wv + k4 * 4);
            float4 pq = *(const float4*)(pr + k4 * 4);
            acc += (double)pq.x * (double)bf2f(u.x);
            acc += (double)pq.y * (double)bf2f(u.y);
            acc += (double)pq.z * (double)bf2f(u.z);
            acc += (double)pq.w * (double)bf2f(u.w);
        }
    }
    return acc;
}

// cheap hi-only approx logit from fragment-major wh: coalesced 16B/lane loads.
// |lt - exact| <= ~(2^-11 + fma slack)*||p||*||w|| (covered by epsH).
__device__ __forceinline__ float hidot(const float* __restrict__ pr,
                                       const f16* __restrict__ whf,
                                       int cc, int rloc, float b2v) {
    const f16* wp = whf + (long)cc * 16384 + rloc * 8;
    float a = 0.f;
    #pragma unroll
    for (int kkg = 0; kkg < 16; ++kkg) {
        half8 hv = *(const half8*)(wp + kkg * 1024);
        float4 p0 = *(const float4*)(pr + kkg * 8);
        float4 p1 = *(const float4*)(pr + kkg * 8 + 4);
        a = fmaf((float)hv[0], p0.x, a);
        a = fmaf((float)hv[1], p0.y, a);
        a = fmaf((float)hv[2], p0.z, a);
        a = fmaf((float)hv[3], p0.w, a);
        a = fmaf((float)hv[4], p1.x, a);
        a = fmaf((float)hv[5], p1.y, a);
        a = fmaf((float)hv[6], p1.z, a);
        a = fmaf((float)hv[7], p1.w, a);
    }
    return fmaf(a, 0.00390625f, b2v);   // /256 + b2
}

// ---------------------------------------------------------------- input dtype sniffer
__global__ void k_detect(const unsigned short* __restrict__ e, int* __restrict__ flag) {
    int i = threadIdx.x;
    unsigned short u = e[2 * i];
    int ex = (u >> 7) & 0xFF;
    bool wild = ((u & 0x7FFF) != 0) && (ex < 0x60 || ex > 0x8F);
    unsigned long long m = __ballot(wild);
    if (i == 0) *flag = (m != 0ull) ? 1 : 0;   // 1 = f32 inputs, 0 = bf16
}

// ---------------------------------------------------------------- transcode ALL f32-bound inputs in one dispatch
struct TCArgs {
    const void* src[12];
    float*      dst[12];
    int         n[12];
};
__global__ __launch_bounds__(256) void k_transcode_all(TCArgs tc, const int* __restrict__ flag) {
    int which = blockIdx.y;
    float* d = tc.dst[which];
    if (d == nullptr) return;
    int i = blockIdx.x * 256 + threadIdx.x;
    if (i >= tc.n[which]) return;
    if (*flag) d[i] = ((const float*)tc.src[which])[i];
    else       d[i] = bf2f(((const unsigned short*)tc.src[which])[i]);
}

// ---------------------------------------------------------------- W2: coalesced norm + scaled f16 hi/lo split (once per launch)
// Emits wh/wl in FRAGMENT-MAJOR order: f16 index = cb*16384 + kkg*1024 + row_local*8 + j
// (cb = vrow/128, row_local = vrow%128, kkg = k/8) — the exact LDS layout
// k_vscan_mfma consumes, so staging is a linear copy.
__global__ __launch_bounds__(256) void k_wsplit(
    const void* __restrict__ W2_raw, unsigned short* __restrict__ wh,
    unsigned short* __restrict__ wl, float* __restrict__ wn,
    const int* __restrict__ flag) {
    int t = blockIdx.x * 256 + threadIdx.x;       // t in [0, V*H/8)
    const bool isf = (*flag != 0);
    int vrow = t >> 4;                            // vocab row
    int kkg  = t & 15;                            // which 8-wide k group
    float v[8];
    if (isf) {
        float4 f0 = ((const float4*)W2_raw)[2 * t];
        float4 f1 = ((const float4*)W2_raw)[2 * t + 1];
        v[0] = f0.x; v[1] = f0.y; v[2] = f0.z; v[3] = f0.w;
        v[4] = f1.x; v[5] = f1.y; v[6] = f1.z; v[7] = f1.w;
    } else {
        ushort8v u = ((const ushort8v*)W2_raw)[t];
        #pragma unroll
        for (int i = 0; i < 8; ++i) v[i] = bf2f(u[i]);
    }
    float s = 0.f;
    half8 hv, lv;
    #pragma unroll
    for (int i = 0; i < 8; ++i) {
        s += v[i] * v[i];
        float ws = v[i] * 256.0f;
        f16 hh = (f16)ws;
        hv[i] = hh;
        lv[i] = (f16)(ws - (float)hh);
    }
    int cb = vrow >> 7, rloc = vrow & 127;
    long dst = (long)cb * 16384 + kkg * 1024 + rloc * 8;
    *(half8*)((f16*)wh + dst) = hv;
    *(half8*)((f16*)wl + dst) = lv;
    // row norm: 16 consecutive threads share a row
    #pragma unroll
    for (int off = 1; off < 16; off <<= 1) s += __shfl_xor(s, off, 64);
    if (kkg == 0) wn[vrow] = sqrtf(s);
}

// ---------------------------------------------------------------- prep: wmax (block 4) + it/unf init (blocks 0-3)
__global__ __launch_bounds__(256) void k_prep(
    const float* __restrict__ wn, float* __restrict__ wmax,
    int* __restrict__ it, int* __restrict__ unf) {
    int tid = threadIdx.x;
    if (blockIdx.x < 4) {
        int i = blockIdx.x * 256 + tid;
        it[i] = SOS; unf[i] = 1;
        return;
    }
    __shared__ float red[4];
    float m = 0.f;
    for (int i = tid; i < V; i += 256) m = fmaxf(m, wn[i]);
    #pragma unroll
    for (int off = 1; off < 64; off <<= 1) m = fmaxf(m, __shfl_xor(m, off, 64));
    if ((tid & 63) == 0) red[tid >> 6] = m;
    __syncthreads();
    if (tid == 0) *wmax = fmaxf(fmaxf(red[0], red[1]), fmaxf(red[2], red[3]));
}

// ---------------------------------------------------------------- hc = fl32(x @ W_fc.T) + b_fc
__global__ __launch_bounds__(256) void k_init_hc(
    const float* __restrict__ xf, const float* __restrict__ Wfc,
    const float* __restrict__ bfc, float* __restrict__ h, float* __restrict__ c) {
    __shared__ float xl[CD];
    int r = blockIdx.x;
    int j = threadIdx.x;
    xl[j] = xf[(long)r * CD + j];
    __syncthreads();
    const float4* w4 = (const float4*)(Wfc + (long)j * CD);
    double acc = 0.0;
    for (int k4 = 0; k4 < CD / 4; ++k4) {
        float4 w = w4[k4];
        int k = k4 * 4;
        acc += (double)xl[k]     * (double)w.x;
        acc += (double)xl[k + 1] * (double)w.y;
        acc += (double)xl[k + 2] * (double)w.z;
        acc += (double)xl[k + 3] * (double)w.w;
    }
    float hc = __fadd_rn((float)acc, bfc[j]);
    if (j < H) h[(long)r * H + j] = hc;
    else       c[(long)r * H + (j - H)] = hc;
}

// ---------------------------------------------------------------- fused F(t-1) + G(t), 512 threads (8 waves/CU):
// Phase F (t>0, waves 0-3): norm-bounded candidate rescue for step t-1.
//   NEW: within each candidate chunk, an element-level hi-only filter
//   (coalesced f16 reads from wh) selects the ~1-2 columns that can be the
//   exact max / equal the max logprob; only those get the bit-identical
//   serial f64 dot from raw W2. Provably includes every element whose exact
//   value the unfiltered version used (threshold AM - eps - epsH).
// Phase G (all 8 waves): unchanged — bit-identical gates/h/c/p32.
__global__ __launch_bounds__(512) void k_gf(
    const float* __restrict__ cmT, const float* __restrict__ csT,
    const void* __restrict__ W2_raw, const unsigned short* __restrict__ whf_,
    const float* __restrict__ b2, const float* __restrict__ wmax,
    const void* __restrict__ embed_raw, float* __restrict__ h, float* __restrict__ c,
    const float* __restrict__ Wih, const float* __restrict__ Whh,
    const float* __restrict__ bih, const float* __restrict__ bhh,
    const float* __restrict__ W1, const float* __restrict__ b1,
    float* __restrict__ p32, unsigned short* __restrict__ ph,
    unsigned short* __restrict__ pl,
    int* __restrict__ it, int* __restrict__ unf, float* __restrict__ out,
    int t, const int* __restrict__ flag) {
    __shared__ float As[4][256];    // concat(e_tok, h) per row
    __shared__ float gsh[4][512];   // gates
    __shared__ float hl[4][132];
    const bool isf = (*flag != 0);
    const f16* whf = (const f16*)whf_;
    int tid = threadIdx.x;
    int rb = blockIdx.x * 4;
    int lane = tid & 63, wid = tid >> 6;

    // ================= F: finalize step t-1 for row rb+wid (waves 0-3) =================
    if (t > 0 && wid < 4) {
        int r = rb + wid;
        const float* pr = p32 + (long)r * H;

        float pa = pr[lane], pb = pr[lane + 64];
        float pn2 = pa * pa + pb * pb;
        #pragma unroll
        for (int off = 1; off < 64; off <<= 1) pn2 += __shfl_xor(pn2, off, 64);
        float pn = sqrtf(pn2);
        float wmx = *wmax;
        // chunk-level window (scan error) and element-level hi-filter window
        float eps  = 6.0e-5f * pn * wmx + 3e-5f;
        float epsH = 7.0e-4f * pn * wmx + 2e-5f;

        float marr[4];
        float AM = -__builtin_inff();
        #pragma unroll
        for (int i = 0; i < 4; ++i) {
            int cc = lane + 64 * i;
            marr[i] = (cc < NCHUNK) ? cmT[(long)cc * B + r] : -__builtin_inff();
            AM = fmaxf(AM, marr[i]);
        }
        #pragma unroll
        for (int off = 1; off < 64; off <<= 1) AM = fmaxf(AM, __shfl_xor(AM, off, 64));
        double S = 0.0;
        #pragma unroll
        for (int i = 0; i < 4; ++i) {
            int cc = lane + 64 * i;
            if (cc < NCHUNK) S += (double)csT[(long)cc * B + r];
        }
        #pragma unroll
        for (int off = 1; off < 64; off <<= 1) S += __shfl_xor(S, off, 64);

        float thr = AM - eps - epsH;

        // pass A: exact max M over hi-filtered elements of candidate chunks
        float M = -__builtin_inff();
        #pragma unroll 1
        for (int i = 0; i < 4; ++i) {
            unsigned long long mask = __ballot(marr[i] >= AM - eps);
            while (mask) {
                int bsl = __ffsll(mask) - 1;
                mask &= mask - 1;
                int cc = i * 64 + bsl;
                #pragma unroll 1
                for (int q = 0; q < 2; ++q) {
                    int v = cc * 128 + q * 64 + lane;
                    float lt = hidot(pr, whf, cc, q * 64 + lane, b2[v]);
                    if (lt >= thr) {
                        double acc = w2dot(pr, W2_raw, v, isf);
                        float l = __fadd_rn((float)acc, b2[v]);
                        M = fmaxf(M, l);
                    }
                }
            }
        }
        #pragma unroll
        for (int off = 1; off < 64; off <<= 1) M = fmaxf(M, __shfl_xor(M, off, 64));

        float L = (float)(log(S) - (double)M);
        float negL = __fsub_rn(0.0f, L);

        // pass B: first v (hi-filtered) whose f32 logprob equals -L
        int best = INT_MAX;
        #pragma unroll 1
        for (int i = 0; i < 4 && best == INT_MAX; ++i) {
            unsigned long long mask = __ballot(marr[i] >= AM - eps);
            while (mask && best == INT_MAX) {
                int bsl = __ffsll(mask) - 1;
                mask &= mask - 1;
                int cc = i * 64 + bsl;
                int hit = INT_MAX;
                #pragma unroll 1
                for (int q = 0; q < 2; ++q) {
                    int v = cc * 128 + q * 64 + lane;
                    float lt = hidot(pr, whf, cc, q * 64 + lane, b2[v]);
                    if (lt >= thr) {
                        double acc = w2dot(pr, W2_raw, v, isf);
                        float l  = __fadd_rn((float)acc, b2[v]);
                        float lp = __fsub_rn(__fsub_rn(l, M), L);
                        if (lp == negL && v < hit) hit = v;
                    }
                }
                #pragma unroll
                for (int off = 1; off < 64; off <<= 1) {
                    int oh = __shfl_xor(hit, off, 64);
                    hit = (oh < hit) ? oh : hit;
                }
                if (hit != INT_MAX) best = hit;
            }
        }
        int bi = (best == INT_MAX) ? 0 : best;

        int unfr = unf[r];
        float lp = negL;
        int itn = unfr ? bi : 0;
        int unfn = (unfr && itn != EOS) ? 1 : 0;
        if (lane == 0) { it[r] = itn; unf[r] = unfn; }
        if (lane < NS) {
            long ro = (long)r * NS + lane;
            int tm1 = t - 1;
            out[ro * T_STEPS + tm1] = (float)itn;
            out[(long)BFULL * T_STEPS + ro * T_STEPS + tm1] = lp;
            out[2L * BFULL * T_STEPS + ro * T_STEPS + tm1] = unfr ? 1.0f : 0.0f;
        }
    }
    __syncthreads();

    // ================= G: gates + cell + proj (rows rb..rb+3) =================
    {   // stage As: thread -> row (tid>>7), 2 consecutive elems
        int r = tid >> 7, kq = (tid & 127) * 2;
        long row = rb + r;
        int tok = it[row];
        float v0, v1;
        if (kq < H) {
            if (isf) {
                float2 f = *(const float2*)((const float*)embed_raw + (long)tok * H + kq);
                v0 = f.x; v1 = f.y;
            } else {
                ushort2 u = *(const ushort2*)((const unsigned short*)embed_raw + (long)tok * H + kq);
                v0 = bf2f(u.x); v1 = bf2f(u.y);
            }
        } else {
            float2 f = *(const float2*)(h + row * H + (kq - H));
            v0 = f.x; v1 = f.y;
        }
        As[r][kq] = v0; As[r][kq + 1] = v1;
    }
    __syncthreads();

    {   // gates: thread owns ONE gate column cg = tid; 4 rows
        int cg = tid;
        double acc[4] = {};
        const float* wi = Wih + (long)cg * H;
        for (int k4 = 0; k4 < H / 4; ++k4) {
            float4 w = *(const float4*)(wi + k4 * 4);
            int k = k4 * 4;
            #pragma unroll
            for (int r = 0; r < 4; ++r) {
                double s0 = acc[r];
                float4 a = *(const float4*)(&As[r][k]);   // broadcast read
                s0 += (double)a.x * (double)w.x;
                s0 += (double)a.y * (double)w.y;
                s0 += (double)a.z * (double)w.z;
                s0 += (double)a.w * (double)w.w;
                acc[r] = s0;
            }
        }
        float t1[4];
        float bi = bih[cg];
        #pragma unroll
        for (int r = 0; r < 4; ++r) {
            t1[r] = __fadd_rn((float)acc[r], bi);
            acc[r] = 0.0;
        }
        const float* wh = Whh + (long)cg * H;
        for (int k4 = 0; k4 < H / 4; ++k4) {
            float4 w = *(const float4*)(wh + k4 * 4);
            int k = H + k4 * 4;
            #pragma unroll
            for (int r = 0; r < 4; ++r) {
                double s0 = acc[r];
                float4 a = *(const float4*)(&As[r][k]);
                s0 += (double)a.x * (double)w.x;
                s0 += (double)a.y * (double)w.y;
                s0 += (double)a.z * (double)w.z;
                s0 += (double)a.w * (double)w.w;
                acc[r] = s0;
            }
        }
        float bh = bhh[cg];
        #pragma unroll
        for (int r = 0; r < 4; ++r)
            gsh[r][cg] = __fadd_rn(__fadd_rn(t1[r], (float)acc[r]), bh);
    }
    __syncthreads();

    {   // cell: one element per thread (4 rows x 128)
        int lr = tid >> 7, j = tid & 127;
        long row = rb + lr;
        float gi = gsh[lr][j], gf = gsh[lr][j + 128], gg = gsh[lr][j + 256], go = gsh[lr][j + 384];
        float cv = c[row * 128 + j];
        float si = sig32(gi);
        float sf = sig32(gf);
        float so = sig32(go);
        float tg = tanh32(gg);
        float cn = __fadd_rn(__fmul_rn(sf, cv), __fmul_rn(si, tg));
        float hn = __fmul_rn(so, tanh32(cn));
        c[row * 128 + j] = cn;
        h[row * 128 + j] = hn;
        hl[lr][j] = hn;
    }
    __syncthreads();

    {   // proj + p-split: thread -> (row tid>>7, col tid&127)
        int j = tid & 127;
        int rr = tid >> 7;
        const float4* w4 = (const float4*)(W1 + (long)j * H);
        double acc = 0.0;
        for (int k4 = 0; k4 < H / 4; ++k4) {
            float4 w = w4[k4];
            int k = k4 * 4;
            acc += (double)hl[rr][k]     * (double)w.x;
            acc += (double)hl[rr][k + 1] * (double)w.y;
            acc += (double)hl[rr][k + 2] * (double)w.z;
            acc += (double)hl[rr][k + 3] * (double)w.w;
        }
        long row = rb + rr;
        float pv = __fadd_rn((float)acc, b1[j]);
        p32[row * H + j] = pv;
        float ps = pv * 256.0f;
        f16 hh = (f16)ps;
        f16 ll = (f16)(ps - (float)hh);
        ((f16*)ph)[row * H + j] = hh;
        ((f16*)pl)[row * H + j] = ll;
    }
}

// ---------------------------------------------------------------- vocab scan via split-f16 MFMA (unchanged):
// 1024 blocks x 256 thr, 4 waves, 2 blocks/CU, XCD-grouped swizzle,
// transposed cm/cs [cb][row] (coalesced writes), global_load_lds staging.
__global__ __launch_bounds__(256, 2) void k_vscan_mfma(
    const unsigned short* __restrict__ ph_, const unsigned short* __restrict__ pl_,
    const unsigned short* __restrict__ whf_, const unsigned short* __restrict__ wlf_,
    const float* __restrict__ b2, float* __restrict__ cmT, float* __restrict__ csT) {
    __shared__ f16 Bsh[16384];   // 32 KB
    __shared__ f16 Bsl[16384];   // 32 KB
    const f16* ph  = (const f16*)ph_;
    const f16* pl  = (const f16*)pl_;
    int tid  = threadIdx.x;
    int lane = tid & 63, wid = tid >> 6;
    int tx = lane & 15, kg = lane >> 4;

    // bid = hi*32 + rb*8 + xcd  ->  cb = hi*8 + xcd  (same cb -> same bid%8 -> same XCD)
    int bid = blockIdx.x;
    int xcd = bid & 7, rb = (bid >> 3) & 3, hi = bid >> 5;
    int cb = hi * 8 + xcd;
    if (cb >= NCHUNK) return;
    int rbw = rb * 256 + wid * 64;
    int vb  = cb * 128;

    // stage B tile: linear 64KB direct-to-LDS (global fragment-major == LDS layout)
    {
        const f16* sh = (const f16*)whf_ + (long)cb * 16384;
        const f16* sl = (const f16*)wlf_ + (long)cb * 16384;
        #pragma unroll
        for (int i = 0; i < 8; ++i) {
            int g = tid + 256 * i;               // 16B chunk id, 0..2047
            __builtin_amdgcn_global_load_lds(
                (const AS1 void*)(const void*)(sh + (long)g * 8),
                (AS3 void*)(void*)(Bsh + g * 8), 16, 0, 0);
            __builtin_amdgcn_global_load_lds(
                (const AS1 void*)(const void*)(sl + (long)g * 8),
                (AS3 void*)(void*)(Bsl + g * 8), 16, 0, 0);
        }
    }
    __syncthreads();

    floatx4 acc[4][8];
    #pragma unroll
    for (int m = 0; m < 4; ++m)
        #pragma unroll
        for (int n = 0; n < 8; ++n)
            acc[m][n] = (floatx4){0.f, 0.f, 0.f, 0.f};

    int aoffs[4];
    #pragma unroll
    for (int m = 0; m < 4; ++m) aoffs[m] = (rbw + m * 16 + tx) * H + kg * 8;

    #pragma unroll
    for (int kk = 0; kk < 4; ++kk) {
        half8 Ah[4], Al[4];
        #pragma unroll
        for (int m = 0; m < 4; ++m) {
            Ah[m] = *(const half8*)(ph + aoffs[m] + kk * 32);
            Al[m] = *(const half8*)(pl + aoffs[m] + kk * 32);
        }
        int bbase = (kk * 4 + kg) * 1024 + tx * 8;
        #pragma unroll
        for (int n = 0; n < 8; ++n) {
            half8 Bh = *(const half8*)(Bsh + bbase + n * 128);
            half8 Bl = *(const half8*)(Bsl + bbase + n * 128);
            #pragma unroll
            for (int m = 0; m < 4; ++m)
                acc[m][n] = __builtin_amdgcn_mfma_f32_16x16x32_f16(Ah[m], Bh, acc[m][n], 0, 0, 0);
            #pragma unroll
            for (int m = 0; m < 4; ++m)
                acc[m][n] = __builtin_amdgcn_mfma_f32_16x16x32_f16(Ah[m], Bl, acc[m][n], 0, 0, 0);
            #pragma unroll
            for (int m = 0; m < 4; ++m)
                acc[m][n] = __builtin_amdgcn_mfma_f32_16x16x32_f16(Al[m], Bh, acc[m][n], 0, 0, 0);
        }
    }

    // epilogue: descale (exact 2^-16), bias, per-(row,chunk) max + expf-sum.
    // C/D layout: col = lane&15 (tx), row = kg*4 + reg. Transposed (coalesced) writes.
    const float S2 = 1.0f / 65536.0f;
    float bb[8];
    #pragma unroll
    for (int n = 0; n < 8; ++n) bb[n] = b2[vb + n * 16 + tx];
    #pragma unroll
    for (int m = 0; m < 4; ++m) {
        #pragma unroll
        for (int r = 0; r < 4; ++r) {
            float mxr = -__builtin_inff();
            float sr = 0.f;
            #pragma unroll
            for (int n = 0; n < 8; ++n) {
                float l = acc[m][n][r] * S2 + bb[n];
                mxr = fmaxf(mxr, l);
                sr += __expf(l);
            }
            #pragma unroll
            for (int off = 1; off < 16; off <<= 1) {
                mxr = fmaxf(mxr, __shfl_xor(mxr, off, 64));
                sr += __shfl_xor(sr, off, 64);
            }
            if (tx == 0) {
                int row = rbw + m * 16 + kg * 4 + r;
                cmT[(long)cb * B + row] = mxr;
                csT[(long)cb * B + row] = sr;
            }
        }
    }
}

// ---------------------------------------------------------------- tail finalize (t = T_STEPS-1), hi-filtered like k_gf's F
__global__ __launch_bounds__(256) void k_final(
    const float* __restrict__ cmT, const float* __restrict__ csT,
    const float* __restrict__ p32, const void* __restrict__ W2_raw,
    const unsigned short* __restrict__ whf_,
    const float* __restrict__ b2, const float* __restrict__ wmax,
    int* __restrict__ it, int* __restrict__ unf,
    float* __restrict__ out, int t, const int* __restrict__ flag) {
    const bool isf = (*flag != 0);
    const f16* whf = (const f16*)whf_;
    int r = blockIdx.x * 4 + (threadIdx.x >> 6);
    int lane = threadIdx.x & 63;
    const float* pr = p32 + (long)r * H;

    float pa = pr[lane], pb = pr[lane + 64];
    float pn2 = pa * pa + pb * pb;
    #pragma unroll
    for (int off = 1; off < 64; off <<= 1) pn2 += __shfl_xor(pn2, off, 64);
    float pn = sqrtf(pn2);
    float wmx = *wmax;
    float eps  = 6.0e-5f * pn * wmx + 3e-5f;
    float epsH = 7.0e-4f * pn * wmx + 2e-5f;

    float marr[4];
    float AM = -__builtin_inff();
    #pragma unroll
    for (int i = 0; i < 4; ++i) {
        int cc = lane + 64 * i;
        marr[i] = (cc < NCHUNK) ? cmT[(long)cc * B + r] : -__builtin_inff();
        AM = fmaxf(AM, marr[i]);
    }
    #pragma unroll
    for (int off = 1; off < 64; off <<= 1) AM = fmaxf(AM, __shfl_xor(AM, off, 64));
    double S = 0.0;
    #pragma unroll
    for (int i = 0; i < 4; ++i) {
        int cc = lane + 64 * i;
        if (cc < NCHUNK) S += (double)csT[(long)cc * B + r];
    }
    #pragma unroll
    for (int off = 1; off < 64; off <<= 1) S += __shfl_xor(S, off, 64);

    float thr = AM - eps - epsH;

    float M = -__builtin_inff();
    #pragma unroll 1
    for (int i = 0; i < 4; ++i) {
        unsigned long long mask = __ballot(marr[i] >= AM - eps);
        while (mask) {
            int b = __ffsll(mask) - 1;
            mask &= mask - 1;
            int cc = i * 64 + b;
            #pragma unroll 1
            for (int q = 0; q < 2; ++q) {
                int v = cc * 128 + q * 64 + lane;
                float lt = hidot(pr, whf, cc, q * 64 + lane, b2[v]);
                if (lt >= thr) {
                    double acc = w2dot(pr, W2_raw, v, isf);
                    float l = __fadd_rn((float)acc, b2[v]);
                    M = fmaxf(M, l);
                }
            }
        }
    }
    #pragma unroll
    for (int off = 1; off < 64; off <<= 1) M = fmaxf(M, __shfl_xor(M, off, 64));

    float L = (float)(log(S) - (double)M);
    float negL = __fsub_rn(0.0f, L);

    int best = INT_MAX;
    #pragma unroll 1
    for (int i = 0; i < 4 && best == INT_MAX; ++i) {
        unsigned long long mask = __ballot(marr[i] >= AM - eps);
        while (mask && best == INT_MAX) {
            int b = __ffsll(mask) - 1;
            mask &= mask - 1;
            int cc = i * 64 + b;
            int hit = INT_MAX;
            #pragma unroll 1
            for (int q = 0; q < 2; ++q) {
                int v = cc * 128 + q * 64 + lane;
                float lt = hidot(pr, whf, cc, q * 64 + lane, b2[v]);
                if (lt >= thr) {
                    double acc = w2dot(pr, W2_raw, v, isf);
                    float l  = __fadd_rn((float)acc, b2[v]);
                    float lp = __fsub_rn(__fsub_rn(l, M), L);
                    if (lp == negL && v < hit) hit = v;
                }
            }
            #pragma unroll
            for (int off = 1; off < 64; off <<= 1) {
                int oh = __shfl_xor(hit, off, 64);
                hit = (oh < hit) ? oh : hit;
            }
            if (hit != INT_MAX) best = hit;
        }
    }
    int bi = (best == INT_MAX) ? 0 : best;

    int unfr = unf[r];
    float lp = negL;
    int itn = unfr ? bi : 0;
    int unfn = (unfr && itn != EOS) ? 1 : 0;
    if (lane == 0) { it[r] = itn; unf[r] = unfn; }
    if (lane < NS) {
        long ro = (long)r * NS + lane;
        out[ro * T_STEPS + t] = (float)itn;
        out[(long)BFULL * T_STEPS + ro * T_STEPS + t] = lp;
        out[2L * BFULL * T_STEPS + ro * T_STEPS + t] = unfr ? 1.0f : 0.0f;
    }
}

// ---------------------------------------------------------------- launch
extern "C" void kernel_launch(void* const* d_in, const int* in_sizes, int n_in,
                              void* d_out, int out_size, void* d_ws, size_t ws_size,
                              hipStream_t stream) {
    float* out = (float*)d_out;

    char* w = (char*)d_ws;
    float* fin[12];
    for (int i = 0; i < 12; ++i) {
        if (i == 1 || i == 10) { fin[i] = nullptr; continue; }   // embed/W2 read raw
        fin[i] = (float*)w;
        size_t bytes = ((size_t)in_sizes[i] * 4 + 15) & ~(size_t)15;
        w += bytes;
    }
    float*  h     = (float*) w; w += (size_t)B * H * 4;
    float*  c     = (float*) w; w += (size_t)B * H * 4;
    float*  p32   = (float*) w; w += (size_t)B * H * 4;
    float*  cm    = (float*) w; w += (size_t)B * NCHUNK * 4;
    float*  cs    = (float*) w; w += (size_t)B * NCHUNK * 4;
    float*  wn    = (float*) w; w += (size_t)V * 4;
    float*  wmax  = (float*) w; w += 16;
    int*    it    = (int*)   w; w += (size_t)B * 4;
    int*    unf   = (int*)   w; w += (size_t)B * 4;
    int*    flag  = (int*)   w; w += 16;
    unsigned short* ph = (unsigned short*)w; w += (size_t)B * H * 2;
    unsigned short* pl = (unsigned short*)w; w += (size_t)B * H * 2;
    unsigned short* wh = (unsigned short*)w; w += (size_t)V * H * 2;
    unsigned short* wl = (unsigned short*)w; w += (size_t)V * H * 2;

    k_detect<<<1, 64, 0, stream>>>((const unsigned short*)d_in[1], flag);

    // one dispatch for all transcodes
    TCArgs tc;
    int maxn = 0;
    for (int i = 0; i < 12; ++i) {
        tc.src[i] = d_in[i];
        tc.dst[i] = fin[i];
        tc.n[i]   = in_sizes[i];
        if (fin[i] && in_sizes[i] > maxn) maxn = in_sizes[i];
    }
    k_transcode_all<<<dim3((maxn + 255) / 256, 12), 256, 0, stream>>>(tc, flag);

    k_wsplit<<<(V * H / 8 + 255) / 256, 256, 0, stream>>>(d_in[10], wh, wl, wn, flag);
    k_prep<<<5, 256, 0, stream>>>(wn, wmax, it, unf);

    const float* xf  = fin[0];
    const float* Wfc = fin[2];
    const float* bfc = fin[3];
    const float* Wih = fin[4];
    const float* bih = fin[5];
    const float* Whh = fin[6];
    const float* bhh = fin[7];
    const float* W1  = fin[8];
    const float* b1  = fin[9];
    const float* b2  = fin[11];

    k_init_hc<<<B, 256, 0, stream>>>(xf, Wfc, bfc, h, c);

    for (int t = 0; t < T_STEPS; ++t) {
        k_gf<<<B / 4, 512, 0, stream>>>(cm, cs, d_in[10], wh, b2, wmax,
                                        d_in[1], h, c, Wih, Whh, bih, bhh,
                                        W1, b1, p32, ph, pl, it, unf, out, t, flag);
        k_vscan_mfma<<<1024, 256, 0, stream>>>(ph, pl, wh, wl, b2, cm, cs);
    }
    k_final<<<B / 4, 256, 0, stream>>>(cm, cs, p32, d_in[10], wh, b2, wmax, it, unf, out,
                                       T_STEPS - 1, flag);
}

// Round 9
// 1656.743 us; speedup vs baseline: 1.9600x; 1.1070x over previous
//
#include <hip/hip_runtime.h>
#include <math.h>
#include <limits.h>

#define H 128
#define V 32000
#define CD 256
#define T_STEPS 21
#define NS 5
#define SOS 1
#define EOS 2
#define B 1024          // unique rows; reference B=5120 is 5 identical copies of each
#define BFULL 5120
#define NCHUNK 250      // V / 128

typedef _Float16 f16;
typedef f16   half8   __attribute__((ext_vector_type(8)));
typedef float floatx4 __attribute__((ext_vector_type(4)));
typedef unsigned short ushort8v __attribute__((ext_vector_type(8)));

#define AS1 __attribute__((address_space(1)))
#define AS3 __attribute__((address_space(3)))

__device__ __forceinline__ float bf2f(unsigned short u) {
    return __uint_as_float(((unsigned)u) << 16);
}

// np-faithful f32 sigmoid/tanh: f64 interior, single f32 round per np op.
__device__ __forceinline__ float sig32(float x) {
    float t = (float)exp(-(double)x);
    float r = __fadd_rn(1.0f, t);
    return __fdiv_rn(1.0f, r);
}
__device__ __forceinline__ float tanh32(float x) { return (float)tanh((double)x); }

// exact f64-recipe dot of p-row (f32, global) with W2 row v, k ascending.
// Vectorized loads; the f64 add order is identical to the scalar loop, so the
// result is bit-identical.
__device__ __forceinline__ double w2dot(const float* __restrict__ pr,
                                        const void* __restrict__ W2_raw,
                                        int v, bool isf) {
    double acc = 0.0;
    if (isf) {
        const float* wv = (const float*)W2_raw + (long)v * H;
        #pragma unroll 8
        for (int k4 = 0; k4 < H / 4; ++k4) {
            float4 wq = *(const float4*)(wv + k4 * 4);
            float4 pq = *(const float4*)(pr + k4 * 4);
            acc += (double)pq.x * (double)wq.x;
            acc += (double)pq.y * (double)wq.y;
            acc += (double)pq.z * (double)wq.z;
            acc += (double)pq.w * (double)wq.w;
        }
    } else {
        const unsigned short* wv = (const unsigned short*)W2_raw + (long)v * H;
        #pragma unroll 8
        for (int k4 = 0; k4 < H / 4; ++k4) {
            ushort4 u = *(const ushort4*)(wv + k4 * 4);
            float4 pq = *(const float4*)(pr + k4 * 4);
            acc += (double)pq.x * (double)bf2f(u.x);
            acc += (double)pq.y * (double)bf2f(u.y);
            acc += (double)pq.z * (double)bf2f(u.z);
            acc += (double)pq.w * (double)bf2f(u.w);
        }
    }
    return acc;
}

// cheap hi-only approx logit from fragment-major wh: coalesced 16B/lane loads.
// |lt - exact| <= ~(2^-11 + fma slack)*||p||*||w|| (covered by epsH).
__device__ __forceinline__ float hidot(const float* __restrict__ pr,
                                       const f16* __restrict__ whf,
                                       int cc, int rloc, float b2v) {
    const f16* wp = whf + (long)cc * 16384 + rloc * 8;
    float a = 0.f;
    #pragma unroll
    for (int kkg = 0; kkg < 16; ++kkg) {
        half8 hv = *(const half8*)(wp + kkg * 1024);
        float4 p0 = *(const float4*)(pr + kkg * 8);
        float4 p1 = *(const float4*)(pr + kkg * 8 + 4);
        a = fmaf((float)hv[0], p0.x, a);
        a = fmaf((float)hv[1], p0.y, a);
        a = fmaf((float)hv[2], p0.z, a);
        a = fmaf((float)hv[3], p0.w, a);
        a = fmaf((float)hv[4], p1.x, a);
        a = fmaf((float)hv[5], p1.y, a);
        a = fmaf((float)hv[6], p1.z, a);
        a = fmaf((float)hv[7], p1.w, a);
    }
    return fmaf(a, 0.00390625f, b2v);   // /256 + b2
}

// ---------------------------------------------------------------- input dtype sniffer
__global__ void k_detect(const unsigned short* __restrict__ e, int* __restrict__ flag) {
    int i = threadIdx.x;
    unsigned short u = e[2 * i];
    int ex = (u >> 7) & 0xFF;
    bool wild = ((u & 0x7FFF) != 0) && (ex < 0x60 || ex > 0x8F);
    unsigned long long m = __ballot(wild);
    if (i == 0) *flag = (m != 0ull) ? 1 : 0;   // 1 = f32 inputs, 0 = bf16
}

// ---------------------------------------------------------------- transcode ALL f32-bound inputs in one dispatch
struct TCArgs {
    const void* src[12];
    float*      dst[12];
    int         n[12];
};
__global__ __launch_bounds__(256) void k_transcode_all(TCArgs tc, const int* __restrict__ flag) {
    int which = blockIdx.y;
    float* d = tc.dst[which];
    if (d == nullptr) return;
    int i = blockIdx.x * 256 + threadIdx.x;
    if (i >= tc.n[which]) return;
    if (*flag) d[i] = ((const float*)tc.src[which])[i];
    else       d[i] = bf2f(((const unsigned short*)tc.src[which])[i]);
}

// ---------------------------------------------------------------- transpose Wih/Whh/W1 to k-pair-major [kp][col][2]
// so the gates/proj weight loads are lane-coalesced (8 B/lane) instead of
// 512 B-strided per lane (64 cache lines per wave instruction). One-time.
__global__ __launch_bounds__(256) void k_wtr(
    const float* __restrict__ Wih, const float* __restrict__ Whh,
    const float* __restrict__ W1, float* __restrict__ wihT,
    float* __restrict__ whhT, float* __restrict__ w1T) {
    int e = blockIdx.x * 256 + threadIdx.x;
    if (e < 512 * 128) {
        int col = e >> 7, k = e & 127;
        wihT[(k >> 1) * 1024 + col * 2 + (k & 1)] = Wih[e];
    } else if (e < 2 * 512 * 128) {
        int i = e - 512 * 128;
        int col = i >> 7, k = i & 127;
        whhT[(k >> 1) * 1024 + col * 2 + (k & 1)] = Whh[i];
    } else if (e < 2 * 512 * 128 + 128 * 128) {
        int i = e - 2 * 512 * 128;
        int col = i >> 7, k = i & 127;
        w1T[(k >> 1) * 256 + col * 2 + (k & 1)] = W1[i];
    }
}

// ---------------------------------------------------------------- W2: coalesced norm + scaled f16 hi/lo split (once per launch)
// Emits wh/wl in FRAGMENT-MAJOR order: f16 index = cb*16384 + kkg*1024 + row_local*8 + j
// (cb = vrow/128, row_local = vrow%128, kkg = k/8) — the exact LDS layout
// k_vscan_mfma consumes, so staging is a linear copy.
__global__ __launch_bounds__(256) void k_wsplit(
    const void* __restrict__ W2_raw, unsigned short* __restrict__ wh,
    unsigned short* __restrict__ wl, float* __restrict__ wn,
    const int* __restrict__ flag) {
    int t = blockIdx.x * 256 + threadIdx.x;       // t in [0, V*H/8)
    const bool isf = (*flag != 0);
    int vrow = t >> 4;                            // vocab row
    int kkg  = t & 15;                            // which 8-wide k group
    float v[8];
    if (isf) {
        float4 f0 = ((const float4*)W2_raw)[2 * t];
        float4 f1 = ((const float4*)W2_raw)[2 * t + 1];
        v[0] = f0.x; v[1] = f0.y; v[2] = f0.z; v[3] = f0.w;
        v[4] = f1.x; v[5] = f1.y; v[6] = f1.z; v[7] = f1.w;
    } else {
        ushort8v u = ((const ushort8v*)W2_raw)[t];
        #pragma unroll
        for (int i = 0; i < 8; ++i) v[i] = bf2f(u[i]);
    }
    float s = 0.f;
    half8 hv, lv;
    #pragma unroll
    for (int i = 0; i < 8; ++i) {
        s += v[i] * v[i];
        float ws = v[i] * 256.0f;
        f16 hh = (f16)ws;
        hv[i] = hh;
        lv[i] = (f16)(ws - (float)hh);
    }
    int cb = vrow >> 7, rloc = vrow & 127;
    long dst = (long)cb * 16384 + kkg * 1024 + rloc * 8;
    *(half8*)((f16*)wh + dst) = hv;
    *(half8*)((f16*)wl + dst) = lv;
    // row norm: 16 consecutive threads share a row
    #pragma unroll
    for (int off = 1; off < 16; off <<= 1) s += __shfl_xor(s, off, 64);
    if (kkg == 0) wn[vrow] = sqrtf(s);
}

// ---------------------------------------------------------------- prep: wmax (block 4) + it/unf init (blocks 0-3)
__global__ __launch_bounds__(256) void k_prep(
    const float* __restrict__ wn, float* __restrict__ wmax,
    int* __restrict__ it, int* __restrict__ unf) {
    int tid = threadIdx.x;
    if (blockIdx.x < 4) {
        int i = blockIdx.x * 256 + tid;
        it[i] = SOS; unf[i] = 1;
        return;
    }
    __shared__ float red[4];
    float m = 0.f;
    for (int i = tid; i < V; i += 256) m = fmaxf(m, wn[i]);
    #pragma unroll
    for (int off = 1; off < 64; off <<= 1) m = fmaxf(m, __shfl_xor(m, off, 64));
    if ((tid & 63) == 0) red[tid >> 6] = m;
    __syncthreads();
    if (tid == 0) *wmax = fmaxf(fmaxf(red[0], red[1]), fmaxf(red[2], red[3]));
}

// ---------------------------------------------------------------- hc = fl32(x @ W_fc.T) + b_fc
__global__ __launch_bounds__(256) void k_init_hc(
    const float* __restrict__ xf, const float* __restrict__ Wfc,
    const float* __restrict__ bfc, float* __restrict__ h, float* __restrict__ c) {
    __shared__ float xl[CD];
    int r = blockIdx.x;
    int j = threadIdx.x;
    xl[j] = xf[(long)r * CD + j];
    __syncthreads();
    const float4* w4 = (const float4*)(Wfc + (long)j * CD);
    double acc = 0.0;
    for (int k4 = 0; k4 < CD / 4; ++k4) {
        float4 w = w4[k4];
        int k = k4 * 4;
        acc += (double)xl[k]     * (double)w.x;
        acc += (double)xl[k + 1] * (double)w.y;
        acc += (double)xl[k + 2] * (double)w.z;
        acc += (double)xl[k + 3] * (double)w.w;
    }
    float hc = __fadd_rn((float)acc, bfc[j]);
    if (j < H) h[(long)r * H + j] = hc;
    else       c[(long)r * H + (j - H)] = hc;
}

// ---------------------------------------------------------------- fused F(t-1) + G(t), 512 threads (8 waves/CU):
// Phase F (t>0, waves 0-3): hi-filtered norm-bounded rescue (round-8).
// Phase G: gates/proj now load TRANSPOSED weights (k-pair-major) —
//   lane-coalesced 8 B loads; f64 chain still strictly k-ascending per
//   output -> bit-identical gates/h/c/p32.
__global__ __launch_bounds__(512) void k_gf(
    const float* __restrict__ cmT, const float* __restrict__ csT,
    const void* __restrict__ W2_raw, const unsigned short* __restrict__ whf_,
    const float* __restrict__ b2, const float* __restrict__ wmax,
    const void* __restrict__ embed_raw, float* __restrict__ h, float* __restrict__ c,
    const float* __restrict__ wihT, const float* __restrict__ whhT,
    const float* __restrict__ bih, const float* __restrict__ bhh,
    const float* __restrict__ w1T, const float* __restrict__ b1,
    float* __restrict__ p32, unsigned short* __restrict__ ph,
    unsigned short* __restrict__ pl,
    int* __restrict__ it, int* __restrict__ unf, float* __restrict__ out,
    int t, const int* __restrict__ flag) {
    __shared__ float As[4][256];    // concat(e_tok, h) per row
    __shared__ float gsh[4][512];   // gates
    __shared__ float hl[4][132];
    const bool isf = (*flag != 0);
    const f16* whf = (const f16*)whf_;
    int tid = threadIdx.x;
    int rb = blockIdx.x * 4;
    int lane = tid & 63, wid = tid >> 6;

    // ================= F: finalize step t-1 for row rb+wid (waves 0-3) =================
    if (t > 0 && wid < 4) {
        int r = rb + wid;
        const float* pr = p32 + (long)r * H;

        float pa = pr[lane], pb = pr[lane + 64];
        float pn2 = pa * pa + pb * pb;
        #pragma unroll
        for (int off = 1; off < 64; off <<= 1) pn2 += __shfl_xor(pn2, off, 64);
        float pn = sqrtf(pn2);
        float wmx = *wmax;
        float eps  = 6.0e-5f * pn * wmx + 3e-5f;
        float epsH = 7.0e-4f * pn * wmx + 2e-5f;

        float marr[4];
        float AM = -__builtin_inff();
        #pragma unroll
        for (int i = 0; i < 4; ++i) {
            int cc = lane + 64 * i;
            marr[i] = (cc < NCHUNK) ? cmT[(long)cc * B + r] : -__builtin_inff();
            AM = fmaxf(AM, marr[i]);
        }
        #pragma unroll
        for (int off = 1; off < 64; off <<= 1) AM = fmaxf(AM, __shfl_xor(AM, off, 64));
        double S = 0.0;
        #pragma unroll
        for (int i = 0; i < 4; ++i) {
            int cc = lane + 64 * i;
            if (cc < NCHUNK) S += (double)csT[(long)cc * B + r];
        }
        #pragma unroll
        for (int off = 1; off < 64; off <<= 1) S += __shfl_xor(S, off, 64);

        float thr = AM - eps - epsH;

        // pass A: exact max M over hi-filtered elements of candidate chunks
        float M = -__builtin_inff();
        #pragma unroll 1
        for (int i = 0; i < 4; ++i) {
            unsigned long long mask = __ballot(marr[i] >= AM - eps);
            while (mask) {
                int bsl = __ffsll(mask) - 1;
                mask &= mask - 1;
                int cc = i * 64 + bsl;
                #pragma unroll 1
                for (int q = 0; q < 2; ++q) {
                    int v = cc * 128 + q * 64 + lane;
                    float lt = hidot(pr, whf, cc, q * 64 + lane, b2[v]);
                    if (lt >= thr) {
                        double acc = w2dot(pr, W2_raw, v, isf);
                        float l = __fadd_rn((float)acc, b2[v]);
                        M = fmaxf(M, l);
                    }
                }
            }
        }
        #pragma unroll
        for (int off = 1; off < 64; off <<= 1) M = fmaxf(M, __shfl_xor(M, off, 64));

        float L = (float)(log(S) - (double)M);
        float negL = __fsub_rn(0.0f, L);

        // pass B: first v (hi-filtered) whose f32 logprob equals -L
        int best = INT_MAX;
        #pragma unroll 1
        for (int i = 0; i < 4 && best == INT_MAX; ++i) {
            unsigned long long mask = __ballot(marr[i] >= AM - eps);
            while (mask && best == INT_MAX) {
                int bsl = __ffsll(mask) - 1;
                mask &= mask - 1;
                int cc = i * 64 + bsl;
                int hit = INT_MAX;
                #pragma unroll 1
                for (int q = 0; q < 2; ++q) {
                    int v = cc * 128 + q * 64 + lane;
                    float lt = hidot(pr, whf, cc, q * 64 + lane, b2[v]);
                    if (lt >= thr) {
                        double acc = w2dot(pr, W2_raw, v, isf);
                        float l  = __fadd_rn((float)acc, b2[v]);
                        float lp = __fsub_rn(__fsub_rn(l, M), L);
                        if (lp == negL && v < hit) hit = v;
                    }
                }
                #pragma unroll
                for (int off = 1; off < 64; off <<= 1) {
                    int oh = __shfl_xor(hit, off, 64);
                    hit = (oh < hit) ? oh : hit;
                }
                if (hit != INT_MAX) best = hit;
            }
        }
        int bi = (best == INT_MAX) ? 0 : best;

        int unfr = unf[r];
        float lp = negL;
        int itn = unfr ? bi : 0;
        int unfn = (unfr && itn != EOS) ? 1 : 0;
        if (lane == 0) { it[r] = itn; unf[r] = unfn; }
        if (lane < NS) {
            long ro = (long)r * NS + lane;
            int tm1 = t - 1;
            out[ro * T_STEPS + tm1] = (float)itn;
            out[(long)BFULL * T_STEPS + ro * T_STEPS + tm1] = lp;
            out[2L * BFULL * T_STEPS + ro * T_STEPS + tm1] = unfr ? 1.0f : 0.0f;
        }
    }
    __syncthreads();

    // ================= G: gates + cell + proj (rows rb..rb+3) =================
    {   // stage As: thread -> row (tid>>7), 2 consecutive elems
        int r = tid >> 7, kq = (tid & 127) * 2;
        long row = rb + r;
        int tok = it[row];
        float v0, v1;
        if (kq < H) {
            if (isf) {
                float2 f = *(const float2*)((const float*)embed_raw + (long)tok * H + kq);
                v0 = f.x; v1 = f.y;
            } else {
                ushort2 u = *(const ushort2*)((const unsigned short*)embed_raw + (long)tok * H + kq);
                v0 = bf2f(u.x); v1 = bf2f(u.y);
            }
        } else {
            float2 f = *(const float2*)(h + row * H + (kq - H));
            v0 = f.x; v1 = f.y;
        }
        As[r][kq] = v0; As[r][kq + 1] = v1;
    }
    __syncthreads();

    {   // gates: thread owns ONE gate column cg = tid; 4 rows; coalesced wT loads
        int cg = tid;
        double acc[4] = {};
        const float2* wi2 = (const float2*)wihT + cg;   // [kp][512] float2
        #pragma unroll 8
        for (int kp = 0; kp < 64; ++kp) {
            float2 w = wi2[kp * 512];
            #pragma unroll
            for (int r = 0; r < 4; ++r) {
                float2 a2 = *(const float2*)(&As[r][kp * 2]);
                double s0 = acc[r];
                s0 += (double)a2.x * (double)w.x;
                s0 += (double)a2.y * (double)w.y;
                acc[r] = s0;
            }
        }
        float t1[4];
        float bi = bih[cg];
        #pragma unroll
        for (int r = 0; r < 4; ++r) {
            t1[r] = __fadd_rn((float)acc[r], bi);
            acc[r] = 0.0;
        }
        const float2* wh2 = (const float2*)whhT + cg;
        #pragma unroll 8
        for (int kp = 0; kp < 64; ++kp) {
            float2 w = wh2[kp * 512];
            #pragma unroll
            for (int r = 0; r < 4; ++r) {
                float2 a2 = *(const float2*)(&As[r][128 + kp * 2]);
                double s0 = acc[r];
                s0 += (double)a2.x * (double)w.x;
                s0 += (double)a2.y * (double)w.y;
                acc[r] = s0;
            }
        }
        float bh = bhh[cg];
        #pragma unroll
        for (int r = 0; r < 4; ++r)
            gsh[r][cg] = __fadd_rn(__fadd_rn(t1[r], (float)acc[r]), bh);
    }
    __syncthreads();

    {   // cell: one element per thread (4 rows x 128)
        int lr = tid >> 7, j = tid & 127;
        long row = rb + lr;
        float gi = gsh[lr][j], gf = gsh[lr][j + 128], gg = gsh[lr][j + 256], go = gsh[lr][j + 384];
        float cv = c[row * 128 + j];
        float si = sig32(gi);
        float sf = sig32(gf);
        float so = sig32(go);
        float tg = tanh32(gg);
        float cn = __fadd_rn(__fmul_rn(sf, cv), __fmul_rn(si, tg));
        float hn = __fmul_rn(so, tanh32(cn));
        c[row * 128 + j] = cn;
        h[row * 128 + j] = hn;
        hl[lr][j] = hn;
    }
    __syncthreads();

    {   // proj + p-split: thread -> (row tid>>7, col tid&127); coalesced w1T loads
        int j = tid & 127;
        int rr = tid >> 7;
        const float2* w12 = (const float2*)w1T + j;     // [kp][128] float2
        double acc = 0.0;
        #pragma unroll 8
        for (int kp = 0; kp < 64; ++kp) {
            float2 w = w12[kp * 128];
            float2 a2 = *(const float2*)(&hl[rr][kp * 2]);
            acc += (double)a2.x * (double)w.x;
            acc += (double)a2.y * (double)w.y;
        }
        long row = rb + rr;
        float pv = __fadd_rn((float)acc, b1[j]);
        p32[row * H + j] = pv;
        float ps = pv * 256.0f;
        f16 hh = (f16)ps;
        f16 ll = (f16)(ps - (float)hh);
        ((f16*)ph)[row * H + j] = hh;
        ((f16*)pl)[row * H + j] = ll;
    }
}

// ---------------------------------------------------------------- vocab scan via split-f16 MFMA (unchanged):
// 1024 blocks x 256 thr, 4 waves, 2 blocks/CU, XCD-grouped swizzle,
// transposed cm/cs [cb][row] (coalesced writes), global_load_lds staging.
__global__ __launch_bounds__(256, 2) void k_vscan_mfma(
    const unsigned short* __restrict__ ph_, const unsigned short* __restrict__ pl_,
    const unsigned short* __restrict__ whf_, const unsigned short* __restrict__ wlf_,
    const float* __restrict__ b2, float* __restrict__ cmT, float* __restrict__ csT) {
    __shared__ f16 Bsh[16384];   // 32 KB
    __shared__ f16 Bsl[16384];   // 32 KB
    const f16* ph  = (const f16*)ph_;
    const f16* pl  = (const f16*)pl_;
    int tid  = threadIdx.x;
    int lane = tid & 63, wid = tid >> 6;
    int tx = lane & 15, kg = lane >> 4;

    // bid = hi*32 + rb*8 + xcd  ->  cb = hi*8 + xcd  (same cb -> same bid%8 -> same XCD)
    int bid = blockIdx.x;
    int xcd = bid & 7, rb = (bid >> 3) & 3, hi = bid >> 5;
    int cb = hi * 8 + xcd;
    if (cb >= NCHUNK) return;
    int rbw = rb * 256 + wid * 64;
    int vb  = cb * 128;

    // stage B tile: linear 64KB direct-to-LDS (global fragment-major == LDS layout)
    {
        const f16* sh = (const f16*)whf_ + (long)cb * 16384;
        const f16* sl = (const f16*)wlf_ + (long)cb * 16384;
        #pragma unroll
        for (int i = 0; i < 8; ++i) {
            int g = tid + 256 * i;               // 16B chunk id, 0..2047
            __builtin_amdgcn_global_load_lds(
                (const AS1 void*)(const void*)(sh + (long)g * 8),
                (AS3 void*)(void*)(Bsh + g * 8), 16, 0, 0);
            __builtin_amdgcn_global_load_lds(
                (const AS1 void*)(const void*)(sl + (long)g * 8),
                (AS3 void*)(void*)(Bsl + g * 8), 16, 0, 0);
        }
    }
    __syncthreads();

    floatx4 acc[4][8];
    #pragma unroll
    for (int m = 0; m < 4; ++m)
        #pragma unroll
        for (int n = 0; n < 8; ++n)
            acc[m][n] = (floatx4){0.f, 0.f, 0.f, 0.f};

    int aoffs[4];
    #pragma unroll
    for (int m = 0; m < 4; ++m) aoffs[m] = (rbw + m * 16 + tx) * H + kg * 8;

    #pragma unroll
    for (int kk = 0; kk < 4; ++kk) {
        half8 Ah[4], Al[4];
        #pragma unroll
        for (int m = 0; m < 4; ++m) {
            Ah[m] = *(const half8*)(ph + aoffs[m] + kk * 32);
            Al[m] = *(const half8*)(pl + aoffs[m] + kk * 32);
        }
        int bbase = (kk * 4 + kg) * 1024 + tx * 8;
        #pragma unroll
        for (int n = 0; n < 8; ++n) {
            half8 Bh = *(const half8*)(Bsh + bbase + n * 128);
            half8 Bl = *(const half8*)(Bsl + bbase + n * 128);
            #pragma unroll
            for (int m = 0; m < 4; ++m)
                acc[m][n] = __builtin_amdgcn_mfma_f32_16x16x32_f16(Ah[m], Bh, acc[m][n], 0, 0, 0);
            #pragma unroll
            for (int m = 0; m < 4; ++m)
                acc[m][n] = __builtin_amdgcn_mfma_f32_16x16x32_f16(Ah[m], Bl, acc[m][n], 0, 0, 0);
            #pragma unroll
            for (int m = 0; m < 4; ++m)
                acc[m][n] = __builtin_amdgcn_mfma_f32_16x16x32_f16(Al[m], Bh, acc[m][n], 0, 0, 0);
        }
    }

    // epilogue: descale (exact 2^-16), bias, per-(row,chunk) max + expf-sum.
    // C/D layout: col = lane&15 (tx), row = kg*4 + reg. Transposed (coalesced) writes.
    const float S2 = 1.0f / 65536.0f;
    float bb[8];
    #pragma unroll
    for (int n = 0; n < 8; ++n) bb[n] = b2[vb + n * 16 + tx];
    #pragma unroll
    for (int m = 0; m < 4; ++m) {
        #pragma unroll
        for (int r = 0; r < 4; ++r) {
            float mxr = -__builtin_inff();
            float sr = 0.f;
            #pragma unroll
            for (int n = 0; n < 8; ++n) {
                float l = acc[m][n][r] * S2 + bb[n];
                mxr = fmaxf(mxr, l);
                sr += __expf(l);
            }
            #pragma unroll
            for (int off = 1; off < 16; off <<= 1) {
                mxr = fmaxf(mxr, __shfl_xor(mxr, off, 64));
                sr += __shfl_xor(sr, off, 64);
            }
            if (tx == 0) {
                int row = rbw + m * 16 + kg * 4 + r;
                cmT[(long)cb * B + row] = mxr;
                csT[(long)cb * B + row] = sr;
            }
        }
    }
}

// ---------------------------------------------------------------- tail finalize (t = T_STEPS-1), hi-filtered
__global__ __launch_bounds__(256) void k_final(
    const float* __restrict__ cmT, const float* __restrict__ csT,
    const float* __restrict__ p32, const void* __restrict__ W2_raw,
    const unsigned short* __restrict__ whf_,
    const float* __restrict__ b2, const float* __restrict__ wmax,
    int* __restrict__ it, int* __restrict__ unf,
    float* __restrict__ out, int t, const int* __restrict__ flag) {
    const bool isf = (*flag != 0);
    const f16* whf = (const f16*)whf_;
    int r = blockIdx.x * 4 + (threadIdx.x >> 6);
    int lane = threadIdx.x & 63;
    const float* pr = p32 + (long)r * H;

    float pa = pr[lane], pb = pr[lane + 64];
    float pn2 = pa * pa + pb * pb;
    #pragma unroll
    for (int off = 1; off < 64; off <<= 1) pn2 += __shfl_xor(pn2, off, 64);
    float pn = sqrtf(pn2);
    float wmx = *wmax;
    float eps  = 6.0e-5f * pn * wmx + 3e-5f;
    float epsH = 7.0e-4f * pn * wmx + 2e-5f;

    float marr[4];
    float AM = -__builtin_inff();
    #pragma unroll
    for (int i = 0; i < 4; ++i) {
        int cc = lane + 64 * i;
        marr[i] = (cc < NCHUNK) ? cmT[(long)cc * B + r] : -__builtin_inff();
        AM = fmaxf(AM, marr[i]);
    }
    #pragma unroll
    for (int off = 1; off < 64; off <<= 1) AM = fmaxf(AM, __shfl_xor(AM, off, 64));
    double S = 0.0;
    #pragma unroll
    for (int i = 0; i < 4; ++i) {
        int cc = lane + 64 * i;
        if (cc < NCHUNK) S += (double)csT[(long)cc * B + r];
    }
    #pragma unroll
    for (int off = 1; off < 64; off <<= 1) S += __shfl_xor(S, off, 64);

    float thr = AM - eps - epsH;

    float M = -__builtin_inff();
    #pragma unroll 1
    for (int i = 0; i < 4; ++i) {
        unsigned long long mask = __ballot(marr[i] >= AM - eps);
        while (mask) {
            int b = __ffsll(mask) - 1;
            mask &= mask - 1;
            int cc = i * 64 + b;
            #pragma unroll 1
            for (int q = 0; q < 2; ++q) {
                int v = cc * 128 + q * 64 + lane;
                float lt = hidot(pr, whf, cc, q * 64 + lane, b2[v]);
                if (lt >= thr) {
                    double acc = w2dot(pr, W2_raw, v, isf);
                    float l = __fadd_rn((float)acc, b2[v]);
                    M = fmaxf(M, l);
                }
            }
        }
    }
    #pragma unroll
    for (int off = 1; off < 64; off <<= 1) M = fmaxf(M, __shfl_xor(M, off, 64));

    float L = (float)(log(S) - (double)M);
    float negL = __fsub_rn(0.0f, L);

    int best = INT_MAX;
    #pragma unroll 1
    for (int i = 0; i < 4 && best == INT_MAX; ++i) {
        unsigned long long mask = __ballot(marr[i] >= AM - eps);
        while (mask && best == INT_MAX) {
            int b = __ffsll(mask) - 1;
            mask &= mask - 1;
            int cc = i * 64 + b;
            int hit = INT_MAX;
            #pragma unroll 1
            for (int q = 0; q < 2; ++q) {
                int v = cc * 128 + q * 64 + lane;
                float lt = hidot(pr, whf, cc, q * 64 + lane, b2[v]);
                if (lt >= thr) {
                    double acc = w2dot(pr, W2_raw, v, isf);
                    float l  = __fadd_rn((float)acc, b2[v]);
                    float lp = __fsub_rn(__fsub_rn(l, M), L);
                    if (lp == negL && v < hit) hit = v;
                }
            }
            #pragma unroll
            for (int off = 1; off < 64; off <<= 1) {
                int oh = __shfl_xor(hit, off, 64);
                hit = (oh < hit) ? oh : hit;
            }
            if (hit != INT_MAX) best = hit;
        }
    }
    int bi = (best == INT_MAX) ? 0 : best;

    int unfr = unf[r];
    float lp = negL;
    int itn = unfr ? bi : 0;
    int unfn = (unfr && itn != EOS) ? 1 : 0;
    if (lane == 0) { it[r] = itn; unf[r] = unfn; }
    if (lane < NS) {
        long ro = (long)r * NS + lane;
        out[ro * T_STEPS + t] = (float)itn;
        out[(long)BFULL * T_STEPS + ro * T_STEPS + t] = lp;
        out[2L * BFULL * T_STEPS + ro * T_STEPS + t] = unfr ? 1.0f : 0.0f;
    }
}

// ---------------------------------------------------------------- launch
extern "C" void kernel_launch(void* const* d_in, const int* in_sizes, int n_in,
                              void* d_out, int out_size, void* d_ws, size_t ws_size,
                              hipStream_t stream) {
    float* out = (float*)d_out;

    char* w = (char*)d_ws;
    float* fin[12];
    for (int i = 0; i < 12; ++i) {
        if (i == 1 || i == 10) { fin[i] = nullptr; continue; }   // embed/W2 read raw
        fin[i] = (float*)w;
        size_t bytes = ((size_t)in_sizes[i] * 4 + 15) & ~(size_t)15;
        w += bytes;
    }
    float*  h     = (float*) w; w += (size_t)B * H * 4;
    float*  c     = (float*) w; w += (size_t)B * H * 4;
    float*  p32   = (float*) w; w += (size_t)B * H * 4;
    float*  cm    = (float*) w; w += (size_t)B * NCHUNK * 4;
    float*  cs    = (float*) w; w += (size_t)B * NCHUNK * 4;
    float*  wn    = (float*) w; w += (size_t)V * 4;
    float*  wmax  = (float*) w; w += 16;
    int*    it    = (int*)   w; w += (size_t)B * 4;
    int*    unf   = (int*)   w; w += (size_t)B * 4;
    int*    flag  = (int*)   w; w += 16;
    float*  wihT  = (float*) w; w += (size_t)512 * 128 * 4;
    float*  whhT  = (float*) w; w += (size_t)512 * 128 * 4;
    float*  w1T   = (float*) w; w += (size_t)128 * 128 * 4;
    unsigned short* ph = (unsigned short*)w; w += (size_t)B * H * 2;
    unsigned short* pl = (unsigned short*)w; w += (size_t)B * H * 2;
    unsigned short* wh = (unsigned short*)w; w += (size_t)V * H * 2;
    unsigned short* wl = (unsigned short*)w; w += (size_t)V * H * 2;

    k_detect<<<1, 64, 0, stream>>>((const unsigned short*)d_in[1], flag);

    // one dispatch for all transcodes
    TCArgs tc;
    int maxn = 0;
    for (int i = 0; i < 12; ++i) {
        tc.src[i] = d_in[i];
        tc.dst[i] = fin[i];
        tc.n[i]   = in_sizes[i];
        if (fin[i] && in_sizes[i] > maxn) maxn = in_sizes[i];
    }
    k_transcode_all<<<dim3((maxn + 255) / 256, 12), 256, 0, stream>>>(tc, flag);

    k_wsplit<<<(V * H / 8 + 255) / 256, 256, 0, stream>>>(d_in[10], wh, wl, wn, flag);
    k_wtr<<<(2 * 512 * 128 + 128 * 128 + 255) / 256, 256, 0, stream>>>(
        fin[4], fin[6], fin[8], wihT, whhT, w1T);
    k_prep<<<5, 256, 0, stream>>>(wn, wmax, it, unf);

    const float* xf  = fin[0];
    const float* Wfc = fin[2];
    const float* bfc = fin[3];
    const float* bih = fin[5];
    const float* bhh = fin[7];
    const float* b1  = fin[9];
    const float* b2  = fin[11];

    k_init_hc<<<B, 256, 0, stream>>>(xf, Wfc, bfc, h, c);

    for (int t = 0; t < T_STEPS; ++t) {
        k_gf<<<B / 4, 512, 0, stream>>>(cm, cs, d_in[10], wh, b2, wmax,
                                        d_in[1], h, c, wihT, whhT, bih, bhh,
                                        w1T, b1, p32, ph, pl, it, unf, out, t, flag);
        k_vscan_mfma<<<1024, 256, 0, stream>>>(ph, pl, wh, wl, b2, cm, cs);
    }
    k_final<<<B / 4, 256, 0, stream>>>(cm, cs, p32, d_in[10], wh, b2, wmax, it, unf, out,
                                       T_STEPS - 1, flag);
}